// Round 1
// 4086.348 us; speedup vs baseline: 1.2899x; 1.2899x over previous
//
#include <hip/hip_runtime.h>

#define DF 200   // feature dim D
#define HC 100   // H*C
#define NH 2     // heads
#define CD 50    // channels per head
#define NG 512   // num graphs

__device__ __forceinline__ float eluf(float x){ return x>0.f ? x : expm1f(x); }

// binary-search node range [start,end) of graph g in sorted batch
__device__ __forceinline__ void seg_range(const int* __restrict__ batch, int N, int g,
                                          int& start, int& end){
  int lo=0, hi=N;
  while(lo<hi){ int m=(lo+hi)>>1; if(batch[m]<g) lo=m+1; else hi=m; }
  start=lo; hi=N;
  while(lo<hi){ int m=(lo+hi)>>1; if(batch[m]<g+1) lo=m+1; else hi=m; }
  end=lo;
}

// ---------------- elementwise elu (f32 -> f32) ----------------
__global__ void k_elu(const float* __restrict__ in, float* __restrict__ out, int n){
  int i = blockIdx.x*blockDim.x + threadIdx.x;
  if(i<n) out[i] = eluf(in[i]);
}

// ---------------- V[k][h] = sum_c W[k][h*50+c]*a[h][c]  (fused attention vec) ----------------
__global__ void k_makeV(const float* __restrict__ W, const float* __restrict__ a, float* __restrict__ V){
  int i = blockIdx.x*blockDim.x + threadIdx.x;
  if(i >= DF*NH) return;
  int k = i>>1, h = i&1;
  float s = 0.f;
  #pragma unroll
  for(int c=0;c<CD;c++) s += W[k*HC + h*CD + c] * a[h*CD + c];
  V[k*2+h] = s;
}

// pack two [200] f32 vectors into V[200][2] (for SAG Wrel|Wroot)
__global__ void k_pack2(const float* __restrict__ a, const float* __restrict__ c, float* __restrict__ V){
  int k = blockIdx.x*blockDim.x + threadIdx.x;
  if(k<DF){ V[k*2] = a[k]; V[k*2+1] = c[k]; }
}

// ---------------- fused 3-pair GEMV: one wave per node, 4 nodes/block ----------------
__global__ void k_gemv3(const float* __restrict__ X,
                        const float* __restrict__ V0, const float* __restrict__ V1, const float* __restrict__ V2,
                        float* __restrict__ o0, float* __restrict__ o1, float* __restrict__ o2, int N){
  int n = blockIdx.x*4 + (threadIdx.x>>6);
  if(n>=N) return;
  int lane = threadIdx.x & 63;
  const float2* xr = (const float2*)(X + (size_t)n*DF);
  float a00=0,a01=0,a10=0,a11=0,a20=0,a21=0;
  for(int k2=lane;k2<DF/2;k2+=64){
    float2 x2 = xr[k2];
    float4 v0 = ((const float4*)V0)[k2];
    float4 v1 = ((const float4*)V1)[k2];
    float4 v2 = ((const float4*)V2)[k2];
    a00 += x2.x*v0.x + x2.y*v0.z;  a01 += x2.x*v0.y + x2.y*v0.w;
    a10 += x2.x*v1.x + x2.y*v1.z;  a11 += x2.x*v1.y + x2.y*v1.w;
    a20 += x2.x*v2.x + x2.y*v2.z;  a21 += x2.x*v2.y + x2.y*v2.w;
  }
  for(int o=32;o;o>>=1){
    a00+=__shfl_down(a00,o); a01+=__shfl_down(a01,o);
    a10+=__shfl_down(a10,o); a11+=__shfl_down(a11,o);
    a20+=__shfl_down(a20,o); a21+=__shfl_down(a21,o);
  }
  if(lane==0){
    o0[n*2]=a00; o0[n*2+1]=a01;
    o1[n*2]=a10; o1[n*2+1]=a11;
    o2[n*2]=a20; o2[n*2+1]=a21;
  }
}

// ---------------- fused 4-pair GEMV ----------------
__global__ void k_gemv4(const float* __restrict__ X,
                        const float* __restrict__ V0, const float* __restrict__ V1,
                        const float* __restrict__ V2, const float* __restrict__ V3,
                        float* __restrict__ o0, float* __restrict__ o1,
                        float* __restrict__ o2, float* __restrict__ o3, int N){
  int n = blockIdx.x*4 + (threadIdx.x>>6);
  if(n>=N) return;
  int lane = threadIdx.x & 63;
  const float2* xr = (const float2*)(X + (size_t)n*DF);
  float a00=0,a01=0,a10=0,a11=0,a20=0,a21=0,a30=0,a31=0;
  for(int k2=lane;k2<DF/2;k2+=64){
    float2 x2 = xr[k2];
    float4 v0 = ((const float4*)V0)[k2];
    float4 v1 = ((const float4*)V1)[k2];
    float4 v2 = ((const float4*)V2)[k2];
    float4 v3 = ((const float4*)V3)[k2];
    a00 += x2.x*v0.x + x2.y*v0.z;  a01 += x2.x*v0.y + x2.y*v0.w;
    a10 += x2.x*v1.x + x2.y*v1.z;  a11 += x2.x*v1.y + x2.y*v1.w;
    a20 += x2.x*v2.x + x2.y*v2.z;  a21 += x2.x*v2.y + x2.y*v2.w;
    a30 += x2.x*v3.x + x2.y*v3.z;  a31 += x2.x*v3.y + x2.y*v3.w;
  }
  for(int o=32;o;o>>=1){
    a00+=__shfl_down(a00,o); a01+=__shfl_down(a01,o);
    a10+=__shfl_down(a10,o); a11+=__shfl_down(a11,o);
    a20+=__shfl_down(a20,o); a21+=__shfl_down(a21,o);
    a30+=__shfl_down(a30,o); a31+=__shfl_down(a31,o);
  }
  if(lane==0){
    o0[n*2]=a00; o0[n*2+1]=a01;
    o1[n*2]=a10; o1[n*2+1]=a11;
    o2[n*2]=a20; o2[n*2+1]=a21;
    o3[n*2]=a30; o3[n*2+1]=a31;
  }
}

// ---------------- out[N,100] = X[N,200] @ W(f32)[200,100] ; 4 cols per thread ----------------
__global__ void k_gemm(const float* __restrict__ X, const float* __restrict__ W,
                       float* __restrict__ out, int N){
  int i = blockIdx.x*blockDim.x + threadIdx.x;
  int total = N*25;
  if(i>=total) return;
  int n = i/25, jg = (i%25)*4;
  const float* xr = X + (size_t)n*DF;
  float a0=0,a1=0,a2=0,a3=0;
  for(int k=0;k<DF;k++){
    float x = xr[k];
    float4 w = *(const float4*)(W + k*HC + jg);   // 16B-aligned: k*100+jg ≡ 0 mod 4
    a0 += x*w.x; a1 += x*w.y; a2 += x*w.z; a3 += x*w.w;
  }
  float* o = out + (size_t)n*HC + jg;
  o[0]=a0; o[1]=a1; o[2]=a2; o[3]=a3;
}

// ---------------- GAT edge scatter: out[d,colOff+f] += e_h * hs[s,f]; z[d,h] += e_h ----------------
__global__ void k_gat_edge(const int* __restrict__ src, const int* __restrict__ dst,
                           int E, int nloop,
                           const float* __restrict__ hs,
                           const float* __restrict__ als, const float* __restrict__ ald,
                           float* __restrict__ z, float* __restrict__ outcat, int colOff){
  int i = blockIdx.x*blockDim.x + threadIdx.x;
  int total = (E+nloop)*HC;
  if(i>=total) return;
  int e = i/HC, f = i%HC;
  int s, d;
  if(e<E){ s = src[e]; d = dst[e]; } else { s = d = e-E; }
  int h = f/CD;
  float lg = als[s*2+h] + ald[d*2+h];
  lg = lg>0.f ? lg : 0.2f*lg;           // leaky_relu(0.2)
  float ev = __expf(lg);
  if(f==0)  atomicAdd(&z[d*2+0], ev);
  if(f==CD) atomicAdd(&z[d*2+1], ev);
  atomicAdd(&outcat[(size_t)d*DF + colOff + f], ev*hs[(size_t)s*HC + f]);
}

// ---------------- fused: GAT finalize (/z + bias) + graph-LN stats, one block per graph ----------------
// replaces k_gat_fin + k_ln_stats; NO atomics (batch is sorted -> binary-searched range)
__global__ void k_fin_stats(float* __restrict__ cat, const float* __restrict__ zA, const float* __restrict__ zB,
                            const float* __restrict__ bA, const float* __restrict__ bB,
                            const int* __restrict__ batch,
                            float* __restrict__ gs, float* __restrict__ gq, float* __restrict__ gc, int N){
  int g = blockIdx.x, start, end;
  seg_range(batch, N, g, start, end);
  float4* c4 = (float4*)cat;
  int i0 = start*(DF/4), i1 = end*(DF/4);
  float s=0.f, q=0.f;
  for(int i=i0+threadIdx.x; i<i1; i+=blockDim.x){
    float4 v = c4[i];
    int j = i*4;
    int n = j/DF, f = j - n*DF;     // float4 never crosses a node row (200%4==0) or the HC split (100%4==0)
    float4 bb; float d0,d1,d2,d3;
    if(f<HC){
      bb = *(const float4*)(bA+f);
      d0 = zA[n*2 +  f   /CD]; d1 = zA[n*2 + (f+1)/CD];
      d2 = zA[n*2 + (f+2)/CD]; d3 = zA[n*2 + (f+3)/CD];
    } else {
      int f2 = f-HC;
      bb = *(const float4*)(bB+f2);
      d0 = zB[n*2 +  f2   /CD]; d1 = zB[n*2 + (f2+1)/CD];
      d2 = zB[n*2 + (f2+2)/CD]; d3 = zB[n*2 + (f2+3)/CD];
    }
    v.x = v.x/(d0+1e-16f)+bb.x;
    v.y = v.y/(d1+1e-16f)+bb.y;
    v.z = v.z/(d2+1e-16f)+bb.z;
    v.w = v.w/(d3+1e-16f)+bb.w;
    c4[i] = v;
    s += v.x+v.y+v.z+v.w;
    q += v.x*v.x+v.y*v.y+v.z*v.z+v.w*v.w;
  }
  for(int o=32;o;o>>=1){ s+=__shfl_down(s,o); q+=__shfl_down(q,o); }
  __shared__ float ss[8], sq[8];
  int wv = threadIdx.x>>6;
  if((threadIdx.x&63)==0){ ss[wv]=s; sq[wv]=q; }
  __syncthreads();
  if(threadIdx.x==0){
    float S=0.f, Q=0.f;
    int nw = blockDim.x>>6;
    for(int k=0;k<nw;k++){ S+=ss[k]; Q+=sq[k]; }
    gs[g]=S; gq[g]=Q; gc[g]=(float)(end-start);
  }
}

// ---------------- fused: graph-LN normalize + elu (in place) + up to 2 attention GEMV pairs ----------------
// one wave per node, 4 nodes/block. V1/o1 may be null (aa path needs only y2).
__global__ void k_ln_norm_f(float* __restrict__ x, const int* __restrict__ batch,
                            const float* __restrict__ gs, const float* __restrict__ gq, const float* __restrict__ gc,
                            const float* __restrict__ wv, const float* __restrict__ bv,
                            const float* __restrict__ V0, float* __restrict__ o0,
                            const float* __restrict__ V1, float* __restrict__ o1, int N){
  int n = blockIdx.x*4 + (threadIdx.x>>6);
  if(n>=N) return;
  int lane = threadIdx.x & 63;
  int g = batch[n];
  float norm = fmaxf(gc[g],1.f)*(float)DF;
  float mean = gs[g]/norm;
  float var  = fmaxf(gq[g]/norm - mean*mean, 0.f);
  float rs   = rsqrtf(var+1e-5f);
  float2* xr = (float2*)(x + (size_t)n*DF);
  float a00=0,a01=0,a10=0,a11=0;
  for(int k2=lane;k2<DF/2;k2+=64){
    float2 x2 = xr[k2];
    float2 w2 = ((const float2*)wv)[k2];
    float2 b2 = ((const float2*)bv)[k2];
    float v0 = eluf((x2.x-mean)*rs*w2.x + b2.x);
    float v1 = eluf((x2.y-mean)*rs*w2.y + b2.y);
    xr[k2] = make_float2(v0,v1);
    float4 vv = ((const float4*)V0)[k2];
    a00 += v0*vv.x + v1*vv.z;  a01 += v0*vv.y + v1*vv.w;
    if(V1){
      float4 u = ((const float4*)V1)[k2];
      a10 += v0*u.x + v1*u.z;  a11 += v0*u.y + v1*u.w;
    }
  }
  for(int o=32;o;o>>=1){
    a00+=__shfl_down(a00,o); a01+=__shfl_down(a01,o);
    a10+=__shfl_down(a10,o); a11+=__shfl_down(a11,o);
  }
  if(lane==0){
    o0[n*2]=a00; o0[n*2+1]=a01;
    if(o1){ o1[n*2]=a10; o1[n*2+1]=a11; }
  }
}

// ---------------- SAG: sagg[dst] += yrel[src] ----------------
__global__ void k_sag_edge(const int* __restrict__ src, const int* __restrict__ dst, int E,
                           const float* __restrict__ y2, float* __restrict__ sagg){
  int e = blockIdx.x*blockDim.x + threadIdx.x;
  if(e<E) atomicAdd(&sagg[dst[e]], y2[src[e]*2]);
}

// ---------------- SAG: en[n]=exp(score); zg[g]+=en ----------------
__global__ void k_sag_exp(const float* __restrict__ sagg, const float* __restrict__ y2,
                          const float* __restrict__ brel,
                          float* __restrict__ en, float* __restrict__ zg,
                          const int* __restrict__ batch, int N){
  int n = blockIdx.x*blockDim.x + threadIdx.x;
  if(n>=N) return;
  float sc = sagg[n] + brel[0] + y2[n*2+1];
  float e = __expf(sc);
  en[n] = e;
  atomicAdd(&zg[batch[n]], e);
}

// ---------------- SAG: out = x * alpha (f32 store to d_out) ----------------
__global__ void k_sag_out(const float* __restrict__ x, const float* __restrict__ en,
                          const float* __restrict__ zg, const int* __restrict__ batch,
                          float* __restrict__ out, int N){
  int i = blockIdx.x*blockDim.x + threadIdx.x;
  if(i>=N*DF) return;
  int n = i/DF;
  float a = en[n]/(zg[batch[n]]+1e-16f);
  out[i] = x[i]*a;
}

// ---------------- per-graph readout: outg[g,f] = (sum_n x[n,f]*en[n]) / zg[g] ----------------
__global__ void k_graph_sum(const float* __restrict__ x, const float* __restrict__ en,
                            const float* __restrict__ zg, const int* __restrict__ batch,
                            float* __restrict__ outg, int N){
  int g = blockIdx.x, start, end;
  seg_range(batch, N, g, start, end);
  int f = threadIdx.x;
  if(f>=DF) return;
  float s = 0.f;
  int n = start;
  for(; n+4<=end; n+=4){   // 4x unroll for memory-level parallelism
    s += x[(size_t) n   *DF+f]*en[n]
       + x[(size_t)(n+1)*DF+f]*en[n+1]
       + x[(size_t)(n+2)*DF+f]*en[n+2]
       + x[(size_t)(n+3)*DF+f]*en[n+3];
  }
  for(; n<end; n++) s += x[(size_t)n*DF+f]*en[n];
  outg[(size_t)g*DF+f] = s/(zg[g]+1e-16f);
}

extern "C" void kernel_launch(void* const* d_in, const int* in_sizes, int n_in,
                              void* d_out, int out_size, void* d_ws, size_t ws_size,
                              hipStream_t stream){
  const float* atom_x    = (const float*)d_in[0];
  const int*   atom_ei   = (const int*)  d_in[1];
  const int*   atom_batch= (const int*)  d_in[2];
  const float* aa_x      = (const float*)d_in[3];
  const int*   aa_ei     = (const int*)  d_in[4];
  /* d_in[5] aa_edge_attr: ignored (GATConv has no edge_dim) */
  const int*   aa_batch  = (const int*)  d_in[6];
  const int*   m2p       = (const int*)  d_in[7];
  const float* Wd     =(const float*)d_in[8];
  const float* ad_src =(const float*)d_in[9];
  const float* ad_dst =(const float*)d_in[10];
  const float* bd     =(const float*)d_in[11];
  const float* Wp     =(const float*)d_in[12];
  const float* ap_src =(const float*)d_in[13];
  const float* ap_dst =(const float*)d_in[14];
  const float* bp     =(const float*)d_in[15];
  const float* Wi_src =(const float*)d_in[16];
  const float* Wi_dst =(const float*)d_in[17];
  const float* ai_src =(const float*)d_in[18];
  const float* ai_dst =(const float*)d_in[19];
  const float* bi     =(const float*)d_in[20];
  const float* ln_d_w =(const float*)d_in[21];
  const float* ln_d_b =(const float*)d_in[22];
  const float* ln_p_w =(const float*)d_in[23];
  const float* ln_p_b =(const float*)d_in[24];
  const float* pd_Wrel=(const float*)d_in[25];
  const float* pd_brel=(const float*)d_in[26];
  const float* pd_Wroot=(const float*)d_in[27];
  const float* pp_Wrel=(const float*)d_in[28];
  const float* pp_brel=(const float*)d_in[29];
  const float* pp_Wroot=(const float*)d_in[30];

  const int nA = in_sizes[0]/DF;     // 25600 atoms
  const int EA = in_sizes[1]/2;      // 102400 atom edges
  const int nP = in_sizes[3]/DF;     // 204800 aa nodes
  const int EP = in_sizes[4]/2;      // 1024000 aa edges
  const int EM = in_sizes[7]/2;      // 512000 m2p edges
  const int nLoop = nA<nP ? nA : nP;

  float* w = (float*)d_ws;
  size_t off = 0;
  auto alloc = [&](size_t n){ float* p = w+off; off += (n+63)&~(size_t)63; return p; };

  float* AX  = alloc((size_t)nA*DF);   // elu(atom_x) -> atom_cat -> atom_h
  float* AB  = alloc((size_t)nP*DF);   // elu(aa_x)   -> aa_cat   -> aa_h
  float* H1  = alloc((size_t)nA*HC);   // h1 (atom@Wd), later hs4 (atom_h@Wi_src)
  float* HS2 = alloc((size_t)nP*HC);   // aa@Wi_src
  float* H3  = alloc((size_t)nP*HC);   // aa@Wp
  float* als1=alloc((size_t)nA*2); float* ald1=alloc((size_t)nA*2);
  float* als2=alloc((size_t)nP*2); float* ald2=alloc((size_t)nA*2);
  float* als3=alloc((size_t)nP*2); float* ald3=alloc((size_t)nP*2);
  float* als4=alloc((size_t)nA*2); float* ald4=alloc((size_t)nP*2);
  float* Vds=alloc(DF*2); float* Vdd=alloc(DF*2);
  float* Vps=alloc(DF*2); float* Vpd=alloc(DF*2);
  float* Vis=alloc(DF*2); float* Vid=alloc(DF*2);
  float* VsA=alloc(DF*2); float* VsP=alloc(DF*2);
  float* y2A=alloc((size_t)nA*2); float* y2P=alloc((size_t)nP*2);
  float* enA=alloc(nA);   float* enP=alloc(nP);
  // ---- contiguous zero region ----
  float* zr0 = w+off;
  float* z1=alloc((size_t)nA*2); float* z2=alloc((size_t)nA*2);
  float* z3=alloc((size_t)nP*2); float* z4=alloc((size_t)nP*2);
  float* gsA=alloc(NG); float* gqA=alloc(NG); float* gcA=alloc(NG);
  float* gsP=alloc(NG); float* gqP=alloc(NG); float* gcP=alloc(NG);
  float* saggA=alloc(nA); float* saggP=alloc(nP);
  float* zgA=alloc(NG); float* zgP=alloc(NG);
  size_t zrBytes = ((w+off) - zr0)*sizeof(float);
  if(off*sizeof(float) > ws_size) return; // workspace too small — bail

  float* out_atom = (float*)d_out;
  float* out_aa   = out_atom + (size_t)nA*DF;
  float* out_dg   = out_aa   + (size_t)nP*DF;
  float* out_pg   = out_dg   + (size_t)NG*DF;

  const int B = 256;
  hipMemsetAsync(zr0, 0, zrBytes, stream);

  // 1. elu
  k_elu<<<(nA*DF+B-1)/B, B, 0, stream>>>(atom_x, AX, nA*DF);
  k_elu<<<(nP*DF+B-1)/B, B, 0, stream>>>(aa_x,   AB, nP*DF);

  // 2. fused attention vectors
  k_makeV<<<2,B,0,stream>>>(Wd,     ad_src, Vds);
  k_makeV<<<2,B,0,stream>>>(Wd,     ad_dst, Vdd);
  k_makeV<<<2,B,0,stream>>>(Wp,     ap_src, Vps);
  k_makeV<<<2,B,0,stream>>>(Wp,     ap_dst, Vpd);
  k_makeV<<<2,B,0,stream>>>(Wi_src, ai_src, Vis);
  k_makeV<<<2,B,0,stream>>>(Wi_dst, ai_dst, Vid);
  k_pack2<<<1,B,0,stream>>>(pd_Wrel, pd_Wroot, VsA);
  k_pack2<<<1,B,0,stream>>>(pp_Wrel, pp_Wroot, VsP);

  // 3. GEMMs + fused attention GEMVs (consume elu buffers)
  k_gemm<<<(nA*25+B-1)/B, B, 0, stream>>>(AX, Wd,     H1,  nA);
  k_gemm<<<(nP*25+B-1)/B, B, 0, stream>>>(AB, Wi_src, HS2, nP);
  k_gemm<<<(nP*25+B-1)/B, B, 0, stream>>>(AB, Wp,     H3,  nP);
  k_gemv3<<<(nA+3)/4,B,0,stream>>>(AX, Vds, Vdd, Vid, als1, ald1, ald2, nA);
  k_gemv4<<<(nP+3)/4,B,0,stream>>>(AB, Vis, Vps, Vpd, Vid, als2, als3, ald3, ald4, nP);

  // 4. zero cat accumulators (reuse AX/AB), scatter GAT1/GAT2/GAT3
  hipMemsetAsync(AX, 0, (size_t)nA*DF*sizeof(float), stream);
  hipMemsetAsync(AB, 0, (size_t)nP*DF*sizeof(float), stream);
  { int tot=(EA+nA)*HC;
    k_gat_edge<<<(tot+B-1)/B,B,0,stream>>>(atom_ei, atom_ei+EA, EA, nA, H1, als1, ald1, z1, AX, 0); }
  { int tot=(EM+nLoop)*HC;  // atom_inter: src=aa(m2p row1), dst=atom(m2p row0)
    k_gat_edge<<<(tot+B-1)/B,B,0,stream>>>(m2p+EM, m2p, EM, nLoop, HS2, als2, ald2, z2, AX, HC); }
  { int tot=(EP+nP)*HC;
    k_gat_edge<<<(tot+B-1)/B,B,0,stream>>>(aa_ei, aa_ei+EP, EP, nP, H3, als3, ald3, z3, AB, 0); }

  // 5. atom: fused finalize + LN-stats (per-graph, no atomics), then fused norm+elu+GEMVs
  k_fin_stats<<<NG,512,0,stream>>>(AX, z1, z2, bd, bi, atom_batch, gsA, gqA, gcA, nA);
  k_ln_norm_f<<<(nA+3)/4,B,0,stream>>>(AX, atom_batch, gsA, gqA, gcA, ln_d_w, ln_d_b,
                                       Vis, als4, VsA, y2A, nA);

  // 6. hs4 = atom_h @ Wi_src (reuse H1); GAT4 scatter
  k_gemm<<<(nA*25+B-1)/B, B, 0, stream>>>(AX, Wi_src, H1, nA);
  { int tot=(EM+nLoop)*HC;  // aa_inter: src=atom(m2p row0), dst=aa(m2p row1)
    k_gat_edge<<<(tot+B-1)/B,B,0,stream>>>(m2p, m2p+EM, EM, nLoop, H1, als4, ald4, z4, AB, HC); }

  // 7. aa: fused finalize + LN-stats, then fused norm+elu+y2 GEMV
  k_fin_stats<<<NG,512,0,stream>>>(AB, z3, z4, bp, bi, aa_batch, gsP, gqP, gcP, nP);
  k_ln_norm_f<<<(nP+3)/4,B,0,stream>>>(AB, aa_batch, gsP, gqP, gcP, ln_p_w, ln_p_b,
                                       VsP, y2P, (const float*)nullptr, (float*)nullptr, nP);

  // 8. SAG pool atom + readout (y2A already computed in step 5)
  k_sag_edge<<<(EA+B-1)/B,B,0,stream>>>(atom_ei, atom_ei+EA, EA, y2A, saggA);
  k_sag_exp<<<(nA+B-1)/B,B,0,stream>>>(saggA, y2A, pd_brel, enA, zgA, atom_batch, nA);
  k_sag_out<<<(nA*DF+B-1)/B,B,0,stream>>>(AX, enA, zgA, atom_batch, out_atom, nA);
  k_graph_sum<<<NG,B,0,stream>>>(AX, enA, zgA, atom_batch, out_dg, nA);

  // 9. SAG pool aa + readout (y2P already computed in step 7)
  k_sag_edge<<<(EP+B-1)/B,B,0,stream>>>(aa_ei, aa_ei+EP, EP, y2P, saggP);
  k_sag_exp<<<(nP+B-1)/B,B,0,stream>>>(saggP, y2P, pp_brel, enP, zgP, aa_batch, nP);
  k_sag_out<<<(nP*DF+B-1)/B,B,0,stream>>>(AB, enP, zgP, aa_batch, out_aa, nP);
  k_graph_sum<<<NG,B,0,stream>>>(AB, enP, zgP, aa_batch, out_pg, nP);
}

// Round 2
// 3210.541 us; speedup vs baseline: 1.6417x; 1.2728x over previous
//
#include <hip/hip_runtime.h>

#define DF 200   // feature dim D
#define HC 100   // H*C
#define NH 2     // heads
#define CD 50    // channels per head
#define NG 512   // num graphs

__device__ __forceinline__ float eluf(float x){ return x>0.f ? x : expm1f(x); }

__device__ __forceinline__ void fma4(float4& a, float s, const float4& w){
  a.x += s*w.x; a.y += s*w.y; a.z += s*w.z; a.w += s*w.w;
}

// binary-search node range [start,end) of graph g in sorted batch
__device__ __forceinline__ void seg_range(const int* __restrict__ batch, int N, int g,
                                          int& start, int& end){
  int lo=0, hi=N;
  while(lo<hi){ int m=(lo+hi)>>1; if(batch[m]<g) lo=m+1; else hi=m; }
  start=lo; hi=N;
  while(lo<hi){ int m=(lo+hi)>>1; if(batch[m]<g+1) lo=m+1; else hi=m; }
  end=lo;
}

// ---------------- elementwise elu (f32 -> f32) ----------------
__global__ void k_elu(const float* __restrict__ in, float* __restrict__ out, int n){
  int i = blockIdx.x*blockDim.x + threadIdx.x;
  if(i<n) out[i] = eluf(in[i]);
}

// ---------------- V[k][h] = sum_c W[k][h*50+c]*a[h][c]  (fused attention vec) ----------------
__global__ void k_makeV(const float* __restrict__ W, const float* __restrict__ a, float* __restrict__ V){
  int i = blockIdx.x*blockDim.x + threadIdx.x;
  if(i >= DF*NH) return;
  int k = i>>1, h = i&1;
  float s = 0.f;
  #pragma unroll
  for(int c=0;c<CD;c++) s += W[k*HC + h*CD + c] * a[h*CD + c];
  V[k*2+h] = s;
}

// pack two [200] f32 vectors into V[200][2] (for SAG Wrel|Wroot)
__global__ void k_pack2(const float* __restrict__ a, const float* __restrict__ c, float* __restrict__ V){
  int k = blockIdx.x*blockDim.x + threadIdx.x;
  if(k<DF){ V[k*2] = a[k]; V[k*2+1] = c[k]; }
}

// ---------------- fused 3-pair GEMV: one wave per node, 4 nodes/block ----------------
__global__ void k_gemv3(const float* __restrict__ X,
                        const float* __restrict__ V0, const float* __restrict__ V1, const float* __restrict__ V2,
                        float* __restrict__ o0, float* __restrict__ o1, float* __restrict__ o2, int N){
  int n = blockIdx.x*4 + (threadIdx.x>>6);
  if(n>=N) return;
  int lane = threadIdx.x & 63;
  const float2* xr = (const float2*)(X + (size_t)n*DF);
  float a00=0,a01=0,a10=0,a11=0,a20=0,a21=0;
  for(int k2=lane;k2<DF/2;k2+=64){
    float2 x2 = xr[k2];
    float4 v0 = ((const float4*)V0)[k2];
    float4 v1 = ((const float4*)V1)[k2];
    float4 v2 = ((const float4*)V2)[k2];
    a00 += x2.x*v0.x + x2.y*v0.z;  a01 += x2.x*v0.y + x2.y*v0.w;
    a10 += x2.x*v1.x + x2.y*v1.z;  a11 += x2.x*v1.y + x2.y*v1.w;
    a20 += x2.x*v2.x + x2.y*v2.z;  a21 += x2.x*v2.y + x2.y*v2.w;
  }
  for(int o=32;o;o>>=1){
    a00+=__shfl_down(a00,o); a01+=__shfl_down(a01,o);
    a10+=__shfl_down(a10,o); a11+=__shfl_down(a11,o);
    a20+=__shfl_down(a20,o); a21+=__shfl_down(a21,o);
  }
  if(lane==0){
    o0[n*2]=a00; o0[n*2+1]=a01;
    o1[n*2]=a10; o1[n*2+1]=a11;
    o2[n*2]=a20; o2[n*2+1]=a21;
  }
}

// ---------------- fused 4-pair GEMV ----------------
__global__ void k_gemv4(const float* __restrict__ X,
                        const float* __restrict__ V0, const float* __restrict__ V1,
                        const float* __restrict__ V2, const float* __restrict__ V3,
                        float* __restrict__ o0, float* __restrict__ o1,
                        float* __restrict__ o2, float* __restrict__ o3, int N){
  int n = blockIdx.x*4 + (threadIdx.x>>6);
  if(n>=N) return;
  int lane = threadIdx.x & 63;
  const float2* xr = (const float2*)(X + (size_t)n*DF);
  float a00=0,a01=0,a10=0,a11=0,a20=0,a21=0,a30=0,a31=0;
  for(int k2=lane;k2<DF/2;k2+=64){
    float2 x2 = xr[k2];
    float4 v0 = ((const float4*)V0)[k2];
    float4 v1 = ((const float4*)V1)[k2];
    float4 v2 = ((const float4*)V2)[k2];
    float4 v3 = ((const float4*)V3)[k2];
    a00 += x2.x*v0.x + x2.y*v0.z;  a01 += x2.x*v0.y + x2.y*v0.w;
    a10 += x2.x*v1.x + x2.y*v1.z;  a11 += x2.x*v1.y + x2.y*v1.w;
    a20 += x2.x*v2.x + x2.y*v2.z;  a21 += x2.x*v2.y + x2.y*v2.w;
    a30 += x2.x*v3.x + x2.y*v3.z;  a31 += x2.x*v3.y + x2.y*v3.w;
  }
  for(int o=32;o;o>>=1){
    a00+=__shfl_down(a00,o); a01+=__shfl_down(a01,o);
    a10+=__shfl_down(a10,o); a11+=__shfl_down(a11,o);
    a20+=__shfl_down(a20,o); a21+=__shfl_down(a21,o);
    a30+=__shfl_down(a30,o); a31+=__shfl_down(a31,o);
  }
  if(lane==0){
    o0[n*2]=a00; o0[n*2+1]=a01;
    o1[n*2]=a10; o1[n*2+1]=a11;
    o2[n*2]=a20; o2[n*2+1]=a21;
    o3[n*2]=a30; o3[n*2+1]=a31;
  }
}

// ---------------- out[N,100] = X[N,200] @ W[200,100] ; 4x4 register tile per thread ----------------
// thread = (node-quad, colgroup of 4): per 4-k step, 8 independent float4 loads feed 64 FMAs.
__global__ void k_gemm(const float* __restrict__ X, const float* __restrict__ W,
                       float* __restrict__ out, int N){
  int i = blockIdx.x*blockDim.x + threadIdx.x;
  int nq4 = (N+3)>>2;
  if(i >= nq4*25) return;
  int nq = i/25, cg = i%25;
  int n0 = nq*4;
  int r1 = min(n0+1,N-1), r2 = min(n0+2,N-1), r3 = min(n0+3,N-1);
  const float* x0 = X + (size_t)n0*DF;
  const float* x1 = X + (size_t)r1*DF;
  const float* x2 = X + (size_t)r2*DF;
  const float* x3 = X + (size_t)r3*DF;
  const float* wp = W + cg*4;
  float4 a0={0,0,0,0}, a1={0,0,0,0}, a2={0,0,0,0}, a3={0,0,0,0};
  for(int k=0;k<DF;k+=4){
    float4 xa = *(const float4*)(x0 + k);
    float4 xb = *(const float4*)(x1 + k);
    float4 xc = *(const float4*)(x2 + k);
    float4 xd = *(const float4*)(x3 + k);
    float4 w0 = *(const float4*)(wp + (k  )*HC);
    float4 w1 = *(const float4*)(wp + (k+1)*HC);
    float4 w2 = *(const float4*)(wp + (k+2)*HC);
    float4 w3 = *(const float4*)(wp + (k+3)*HC);
    fma4(a0,xa.x,w0); fma4(a0,xa.y,w1); fma4(a0,xa.z,w2); fma4(a0,xa.w,w3);
    fma4(a1,xb.x,w0); fma4(a1,xb.y,w1); fma4(a1,xb.z,w2); fma4(a1,xb.w,w3);
    fma4(a2,xc.x,w0); fma4(a2,xc.y,w1); fma4(a2,xc.z,w2); fma4(a2,xc.w,w3);
    fma4(a3,xd.x,w0); fma4(a3,xd.y,w1); fma4(a3,xd.z,w2); fma4(a3,xd.w,w3);
  }
  float* o = out + (size_t)n0*HC + cg*4;
  *(float4*)(o) = a0;
  if(n0+1<N) *(float4*)(o+HC)   = a1;
  if(n0+2<N) *(float4*)(o+2*HC) = a2;
  if(n0+3<N) *(float4*)(o+3*HC) = a3;
}

// ---------------- fused dual GEMM: out1 = X@W1, out2 = X@W2 (X read once) ----------------
__global__ void k_gemm2(const float* __restrict__ X,
                        const float* __restrict__ W1, const float* __restrict__ W2,
                        float* __restrict__ out1, float* __restrict__ out2, int N){
  int i = blockIdx.x*blockDim.x + threadIdx.x;
  int nq4 = (N+3)>>2;
  if(i >= nq4*25) return;
  int nq = i/25, cg = i%25;
  int n0 = nq*4;
  int r1 = min(n0+1,N-1), r2 = min(n0+2,N-1), r3 = min(n0+3,N-1);
  const float* x0 = X + (size_t)n0*DF;
  const float* x1 = X + (size_t)r1*DF;
  const float* x2 = X + (size_t)r2*DF;
  const float* x3 = X + (size_t)r3*DF;
  const float* wp1 = W1 + cg*4;
  const float* wp2 = W2 + cg*4;
  float4 a0={0,0,0,0}, a1={0,0,0,0}, a2={0,0,0,0}, a3={0,0,0,0};
  float4 b0={0,0,0,0}, b1={0,0,0,0}, b2={0,0,0,0}, b3={0,0,0,0};
  for(int k=0;k<DF;k+=4){
    float4 xa = *(const float4*)(x0 + k);
    float4 xb = *(const float4*)(x1 + k);
    float4 xc = *(const float4*)(x2 + k);
    float4 xd = *(const float4*)(x3 + k);
    float4 u0 = *(const float4*)(wp1 + (k  )*HC);
    float4 u1 = *(const float4*)(wp1 + (k+1)*HC);
    float4 u2 = *(const float4*)(wp1 + (k+2)*HC);
    float4 u3 = *(const float4*)(wp1 + (k+3)*HC);
    float4 v0 = *(const float4*)(wp2 + (k  )*HC);
    float4 v1 = *(const float4*)(wp2 + (k+1)*HC);
    float4 v2 = *(const float4*)(wp2 + (k+2)*HC);
    float4 v3 = *(const float4*)(wp2 + (k+3)*HC);
    fma4(a0,xa.x,u0); fma4(a0,xa.y,u1); fma4(a0,xa.z,u2); fma4(a0,xa.w,u3);
    fma4(a1,xb.x,u0); fma4(a1,xb.y,u1); fma4(a1,xb.z,u2); fma4(a1,xb.w,u3);
    fma4(a2,xc.x,u0); fma4(a2,xc.y,u1); fma4(a2,xc.z,u2); fma4(a2,xc.w,u3);
    fma4(a3,xd.x,u0); fma4(a3,xd.y,u1); fma4(a3,xd.z,u2); fma4(a3,xd.w,u3);
    fma4(b0,xa.x,v0); fma4(b0,xa.y,v1); fma4(b0,xa.z,v2); fma4(b0,xa.w,v3);
    fma4(b1,xb.x,v0); fma4(b1,xb.y,v1); fma4(b1,xb.z,v2); fma4(b1,xb.w,v3);
    fma4(b2,xc.x,v0); fma4(b2,xc.y,v1); fma4(b2,xc.z,v2); fma4(b2,xc.w,v3);
    fma4(b3,xd.x,v0); fma4(b3,xd.y,v1); fma4(b3,xd.z,v2); fma4(b3,xd.w,v3);
  }
  float* o1 = out1 + (size_t)n0*HC + cg*4;
  float* o2 = out2 + (size_t)n0*HC + cg*4;
  *(float4*)(o1) = a0;
  *(float4*)(o2) = b0;
  if(n0+1<N){ *(float4*)(o1+HC)   = a1; *(float4*)(o2+HC)   = b1; }
  if(n0+2<N){ *(float4*)(o1+2*HC) = a2; *(float4*)(o2+2*HC) = b2; }
  if(n0+3<N){ *(float4*)(o1+3*HC) = a3; *(float4*)(o2+3*HC) = b3; }
}

// ---------------- GAT edge scatter: out[d,colOff+f] += e_h * hs[s,f]; z[d,h] += e_h ----------------
__global__ void k_gat_edge(const int* __restrict__ src, const int* __restrict__ dst,
                           int E, int nloop,
                           const float* __restrict__ hs,
                           const float* __restrict__ als, const float* __restrict__ ald,
                           float* __restrict__ z, float* __restrict__ outcat, int colOff){
  int i = blockIdx.x*blockDim.x + threadIdx.x;
  int total = (E+nloop)*HC;
  if(i>=total) return;
  int e = i/HC, f = i%HC;
  int s, d;
  if(e<E){ s = src[e]; d = dst[e]; } else { s = d = e-E; }
  int h = f/CD;
  float lg = als[s*2+h] + ald[d*2+h];
  lg = lg>0.f ? lg : 0.2f*lg;           // leaky_relu(0.2)
  float ev = __expf(lg);
  if(f==0)  atomicAdd(&z[d*2+0], ev);
  if(f==CD) atomicAdd(&z[d*2+1], ev);
  atomicAdd(&outcat[(size_t)d*DF + colOff + f], ev*hs[(size_t)s*HC + f]);
}

// ---------------- fused: GAT finalize (/z + bias) + graph-LN stats, one block per graph ----------------
__global__ void k_fin_stats(float* __restrict__ cat, const float* __restrict__ zA, const float* __restrict__ zB,
                            const float* __restrict__ bA, const float* __restrict__ bB,
                            const int* __restrict__ batch,
                            float* __restrict__ gs, float* __restrict__ gq, float* __restrict__ gc, int N){
  int g = blockIdx.x, start, end;
  seg_range(batch, N, g, start, end);
  float4* c4 = (float4*)cat;
  int i0 = start*(DF/4), i1 = end*(DF/4);
  float s=0.f, q=0.f;
  for(int i=i0+threadIdx.x; i<i1; i+=blockDim.x){
    float4 v = c4[i];
    int j = i*4;
    int n = j/DF, f = j - n*DF;     // float4 never crosses a node row (200%4==0) or the HC split (100%4==0)
    float4 bb; float d0,d1,d2,d3;
    if(f<HC){
      bb = *(const float4*)(bA+f);
      d0 = zA[n*2 +  f   /CD]; d1 = zA[n*2 + (f+1)/CD];
      d2 = zA[n*2 + (f+2)/CD]; d3 = zA[n*2 + (f+3)/CD];
    } else {
      int f2 = f-HC;
      bb = *(const float4*)(bB+f2);
      d0 = zB[n*2 +  f2   /CD]; d1 = zB[n*2 + (f2+1)/CD];
      d2 = zB[n*2 + (f2+2)/CD]; d3 = zB[n*2 + (f2+3)/CD];
    }
    v.x = v.x/(d0+1e-16f)+bb.x;
    v.y = v.y/(d1+1e-16f)+bb.y;
    v.z = v.z/(d2+1e-16f)+bb.z;
    v.w = v.w/(d3+1e-16f)+bb.w;
    c4[i] = v;
    s += v.x+v.y+v.z+v.w;
    q += v.x*v.x+v.y*v.y+v.z*v.z+v.w*v.w;
  }
  for(int o=32;o;o>>=1){ s+=__shfl_down(s,o); q+=__shfl_down(q,o); }
  __shared__ float ss[8], sq[8];
  int wv = threadIdx.x>>6;
  if((threadIdx.x&63)==0){ ss[wv]=s; sq[wv]=q; }
  __syncthreads();
  if(threadIdx.x==0){
    float S=0.f, Q=0.f;
    int nw = blockDim.x>>6;
    for(int k=0;k<nw;k++){ S+=ss[k]; Q+=sq[k]; }
    gs[g]=S; gq[g]=Q; gc[g]=(float)(end-start);
  }
}

// ---------------- fused: graph-LN normalize + elu (in place) + up to 2 attention GEMV pairs ----------------
__global__ void k_ln_norm_f(float* __restrict__ x, const int* __restrict__ batch,
                            const float* __restrict__ gs, const float* __restrict__ gq, const float* __restrict__ gc,
                            const float* __restrict__ wv, const float* __restrict__ bv,
                            const float* __restrict__ V0, float* __restrict__ o0,
                            const float* __restrict__ V1, float* __restrict__ o1, int N){
  int n = blockIdx.x*4 + (threadIdx.x>>6);
  if(n>=N) return;
  int lane = threadIdx.x & 63;
  int g = batch[n];
  float norm = fmaxf(gc[g],1.f)*(float)DF;
  float mean = gs[g]/norm;
  float var  = fmaxf(gq[g]/norm - mean*mean, 0.f);
  float rs   = rsqrtf(var+1e-5f);
  float2* xr = (float2*)(x + (size_t)n*DF);
  float a00=0,a01=0,a10=0,a11=0;
  for(int k2=lane;k2<DF/2;k2+=64){
    float2 x2 = xr[k2];
    float2 w2 = ((const float2*)wv)[k2];
    float2 b2 = ((const float2*)bv)[k2];
    float v0 = eluf((x2.x-mean)*rs*w2.x + b2.x);
    float v1 = eluf((x2.y-mean)*rs*w2.y + b2.y);
    xr[k2] = make_float2(v0,v1);
    float4 vv = ((const float4*)V0)[k2];
    a00 += v0*vv.x + v1*vv.z;  a01 += v0*vv.y + v1*vv.w;
    if(V1){
      float4 u = ((const float4*)V1)[k2];
      a10 += v0*u.x + v1*u.z;  a11 += v0*u.y + v1*u.w;
    }
  }
  for(int o=32;o;o>>=1){
    a00+=__shfl_down(a00,o); a01+=__shfl_down(a01,o);
    a10+=__shfl_down(a10,o); a11+=__shfl_down(a11,o);
  }
  if(lane==0){
    o0[n*2]=a00; o0[n*2+1]=a01;
    if(o1){ o1[n*2]=a10; o1[n*2+1]=a11; }
  }
}

// ---------------- SAG: sagg[dst] += yrel[src] ----------------
__global__ void k_sag_edge(const int* __restrict__ src, const int* __restrict__ dst, int E,
                           const float* __restrict__ y2, float* __restrict__ sagg){
  int e = blockIdx.x*blockDim.x + threadIdx.x;
  if(e<E) atomicAdd(&sagg[dst[e]], y2[src[e]*2]);
}

// ---------------- SAG: en[n]=exp(score); zg[g]+=en ----------------
__global__ void k_sag_exp(const float* __restrict__ sagg, const float* __restrict__ y2,
                          const float* __restrict__ brel,
                          float* __restrict__ en, float* __restrict__ zg,
                          const int* __restrict__ batch, int N){
  int n = blockIdx.x*blockDim.x + threadIdx.x;
  if(n>=N) return;
  float sc = sagg[n] + brel[0] + y2[n*2+1];
  float e = __expf(sc);
  en[n] = e;
  atomicAdd(&zg[batch[n]], e);
}

// ---------------- SAG: out = x * alpha (f32 store to d_out) ----------------
__global__ void k_sag_out(const float* __restrict__ x, const float* __restrict__ en,
                          const float* __restrict__ zg, const int* __restrict__ batch,
                          float* __restrict__ out, int N){
  int i = blockIdx.x*blockDim.x + threadIdx.x;
  if(i>=N*DF) return;
  int n = i/DF;
  float a = en[n]/(zg[batch[n]]+1e-16f);
  out[i] = x[i]*a;
}

// ---------------- per-graph readout: outg[g,f] = (sum_n x[n,f]*en[n]) / zg[g] ----------------
__global__ void k_graph_sum(const float* __restrict__ x, const float* __restrict__ en,
                            const float* __restrict__ zg, const int* __restrict__ batch,
                            float* __restrict__ outg, int N){
  int g = blockIdx.x, start, end;
  seg_range(batch, N, g, start, end);
  int f = threadIdx.x;
  if(f>=DF) return;
  float s = 0.f;
  int n = start;
  for(; n+4<=end; n+=4){   // 4x unroll for memory-level parallelism
    s += x[(size_t) n   *DF+f]*en[n]
       + x[(size_t)(n+1)*DF+f]*en[n+1]
       + x[(size_t)(n+2)*DF+f]*en[n+2]
       + x[(size_t)(n+3)*DF+f]*en[n+3];
  }
  for(; n<end; n++) s += x[(size_t)n*DF+f]*en[n];
  outg[(size_t)g*DF+f] = s/(zg[g]+1e-16f);
}

extern "C" void kernel_launch(void* const* d_in, const int* in_sizes, int n_in,
                              void* d_out, int out_size, void* d_ws, size_t ws_size,
                              hipStream_t stream){
  const float* atom_x    = (const float*)d_in[0];
  const int*   atom_ei   = (const int*)  d_in[1];
  const int*   atom_batch= (const int*)  d_in[2];
  const float* aa_x      = (const float*)d_in[3];
  const int*   aa_ei     = (const int*)  d_in[4];
  /* d_in[5] aa_edge_attr: ignored (GATConv has no edge_dim) */
  const int*   aa_batch  = (const int*)  d_in[6];
  const int*   m2p       = (const int*)  d_in[7];
  const float* Wd     =(const float*)d_in[8];
  const float* ad_src =(const float*)d_in[9];
  const float* ad_dst =(const float*)d_in[10];
  const float* bd     =(const float*)d_in[11];
  const float* Wp     =(const float*)d_in[12];
  const float* ap_src =(const float*)d_in[13];
  const float* ap_dst =(const float*)d_in[14];
  const float* bp     =(const float*)d_in[15];
  const float* Wi_src =(const float*)d_in[16];
  const float* Wi_dst =(const float*)d_in[17];
  const float* ai_src =(const float*)d_in[18];
  const float* ai_dst =(const float*)d_in[19];
  const float* bi     =(const float*)d_in[20];
  const float* ln_d_w =(const float*)d_in[21];
  const float* ln_d_b =(const float*)d_in[22];
  const float* ln_p_w =(const float*)d_in[23];
  const float* ln_p_b =(const float*)d_in[24];
  const float* pd_Wrel=(const float*)d_in[25];
  const float* pd_brel=(const float*)d_in[26];
  const float* pd_Wroot=(const float*)d_in[27];
  const float* pp_Wrel=(const float*)d_in[28];
  const float* pp_brel=(const float*)d_in[29];
  const float* pp_Wroot=(const float*)d_in[30];

  const int nA = in_sizes[0]/DF;     // 25600 atoms
  const int EA = in_sizes[1]/2;      // 102400 atom edges
  const int nP = in_sizes[3]/DF;     // 204800 aa nodes
  const int EP = in_sizes[4]/2;      // 1024000 aa edges
  const int EM = in_sizes[7]/2;      // 512000 m2p edges
  const int nLoop = nA<nP ? nA : nP;

  float* w = (float*)d_ws;
  size_t off = 0;
  auto alloc = [&](size_t n){ float* p = w+off; off += (n+63)&~(size_t)63; return p; };

  float* AX  = alloc((size_t)nA*DF);   // elu(atom_x) -> atom_cat -> atom_h
  float* AB  = alloc((size_t)nP*DF);   // elu(aa_x)   -> aa_cat   -> aa_h
  float* H1  = alloc((size_t)nA*HC);   // h1 (atom@Wd), later hs4 (atom_h@Wi_src)
  float* HS2 = alloc((size_t)nP*HC);   // aa@Wi_src
  float* H3  = alloc((size_t)nP*HC);   // aa@Wp
  float* als1=alloc((size_t)nA*2); float* ald1=alloc((size_t)nA*2);
  float* als2=alloc((size_t)nP*2); float* ald2=alloc((size_t)nA*2);
  float* als3=alloc((size_t)nP*2); float* ald3=alloc((size_t)nP*2);
  float* als4=alloc((size_t)nA*2); float* ald4=alloc((size_t)nP*2);
  float* Vds=alloc(DF*2); float* Vdd=alloc(DF*2);
  float* Vps=alloc(DF*2); float* Vpd=alloc(DF*2);
  float* Vis=alloc(DF*2); float* Vid=alloc(DF*2);
  float* VsA=alloc(DF*2); float* VsP=alloc(DF*2);
  float* y2A=alloc((size_t)nA*2); float* y2P=alloc((size_t)nP*2);
  float* enA=alloc(nA);   float* enP=alloc(nP);
  // ---- contiguous zero region ----
  float* zr0 = w+off;
  float* z1=alloc((size_t)nA*2); float* z2=alloc((size_t)nA*2);
  float* z3=alloc((size_t)nP*2); float* z4=alloc((size_t)nP*2);
  float* gsA=alloc(NG); float* gqA=alloc(NG); float* gcA=alloc(NG);
  float* gsP=alloc(NG); float* gqP=alloc(NG); float* gcP=alloc(NG);
  float* saggA=alloc(nA); float* saggP=alloc(nP);
  float* zgA=alloc(NG); float* zgP=alloc(NG);
  size_t zrBytes = ((w+off) - zr0)*sizeof(float);
  if(off*sizeof(float) > ws_size) return; // workspace too small — bail

  float* out_atom = (float*)d_out;
  float* out_aa   = out_atom + (size_t)nA*DF;
  float* out_dg   = out_aa   + (size_t)nP*DF;
  float* out_pg   = out_dg   + (size_t)NG*DF;

  const int B = 256;
  hipMemsetAsync(zr0, 0, zrBytes, stream);

  // 1. elu
  k_elu<<<(nA*DF+B-1)/B, B, 0, stream>>>(atom_x, AX, nA*DF);
  k_elu<<<(nP*DF+B-1)/B, B, 0, stream>>>(aa_x,   AB, nP*DF);

  // 2. fused attention vectors
  k_makeV<<<2,B,0,stream>>>(Wd,     ad_src, Vds);
  k_makeV<<<2,B,0,stream>>>(Wd,     ad_dst, Vdd);
  k_makeV<<<2,B,0,stream>>>(Wp,     ap_src, Vps);
  k_makeV<<<2,B,0,stream>>>(Wp,     ap_dst, Vpd);
  k_makeV<<<2,B,0,stream>>>(Wi_src, ai_src, Vis);
  k_makeV<<<2,B,0,stream>>>(Wi_dst, ai_dst, Vid);
  k_pack2<<<1,B,0,stream>>>(pd_Wrel, pd_Wroot, VsA);
  k_pack2<<<1,B,0,stream>>>(pp_Wrel, pp_Wroot, VsP);

  // 3. GEMMs (4x4 register tiled; the two nP GEMMs fused to read X once) + attention GEMVs
  { int tot = ((nA+3)/4)*25;
    k_gemm<<<(tot+B-1)/B, B, 0, stream>>>(AX, Wd, H1, nA); }
  { int tot = ((nP+3)/4)*25;
    k_gemm2<<<(tot+B-1)/B, B, 0, stream>>>(AB, Wi_src, Wp, HS2, H3, nP); }
  k_gemv3<<<(nA+3)/4,B,0,stream>>>(AX, Vds, Vdd, Vid, als1, ald1, ald2, nA);
  k_gemv4<<<(nP+3)/4,B,0,stream>>>(AB, Vis, Vps, Vpd, Vid, als2, als3, ald3, ald4, nP);

  // 4. zero cat accumulators (reuse AX/AB), scatter GAT1/GAT2/GAT3
  hipMemsetAsync(AX, 0, (size_t)nA*DF*sizeof(float), stream);
  hipMemsetAsync(AB, 0, (size_t)nP*DF*sizeof(float), stream);
  { int tot=(EA+nA)*HC;
    k_gat_edge<<<(tot+B-1)/B,B,0,stream>>>(atom_ei, atom_ei+EA, EA, nA, H1, als1, ald1, z1, AX, 0); }
  { int tot=(EM+nLoop)*HC;  // atom_inter: src=aa(m2p row1), dst=atom(m2p row0)
    k_gat_edge<<<(tot+B-1)/B,B,0,stream>>>(m2p+EM, m2p, EM, nLoop, HS2, als2, ald2, z2, AX, HC); }
  { int tot=(EP+nP)*HC;
    k_gat_edge<<<(tot+B-1)/B,B,0,stream>>>(aa_ei, aa_ei+EP, EP, nP, H3, als3, ald3, z3, AB, 0); }

  // 5. atom: fused finalize + LN-stats (per-graph, no atomics), then fused norm+elu+GEMVs
  k_fin_stats<<<NG,512,0,stream>>>(AX, z1, z2, bd, bi, atom_batch, gsA, gqA, gcA, nA);
  k_ln_norm_f<<<(nA+3)/4,B,0,stream>>>(AX, atom_batch, gsA, gqA, gcA, ln_d_w, ln_d_b,
                                       Vis, als4, VsA, y2A, nA);

  // 6. hs4 = atom_h @ Wi_src (reuse H1); GAT4 scatter
  { int tot = ((nA+3)/4)*25;
    k_gemm<<<(tot+B-1)/B, B, 0, stream>>>(AX, Wi_src, H1, nA); }
  { int tot=(EM+nLoop)*HC;  // aa_inter: src=atom(m2p row0), dst=aa(m2p row1)
    k_gat_edge<<<(tot+B-1)/B,B,0,stream>>>(m2p, m2p+EM, EM, nLoop, H1, als4, ald4, z4, AB, HC); }

  // 7. aa: fused finalize + LN-stats, then fused norm+elu+y2 GEMV
  k_fin_stats<<<NG,512,0,stream>>>(AB, z3, z4, bp, bi, aa_batch, gsP, gqP, gcP, nP);
  k_ln_norm_f<<<(nP+3)/4,B,0,stream>>>(AB, aa_batch, gsP, gqP, gcP, ln_p_w, ln_p_b,
                                       VsP, y2P, (const float*)nullptr, (float*)nullptr, nP);

  // 8. SAG pool atom + readout (y2A already computed in step 5)
  k_sag_edge<<<(EA+B-1)/B,B,0,stream>>>(atom_ei, atom_ei+EA, EA, y2A, saggA);
  k_sag_exp<<<(nA+B-1)/B,B,0,stream>>>(saggA, y2A, pd_brel, enA, zgA, atom_batch, nA);
  k_sag_out<<<(nA*DF+B-1)/B,B,0,stream>>>(AX, enA, zgA, atom_batch, out_atom, nA);
  k_graph_sum<<<NG,B,0,stream>>>(AX, enA, zgA, atom_batch, out_dg, nA);

  // 9. SAG pool aa + readout (y2P already computed in step 7)
  k_sag_edge<<<(EP+B-1)/B,B,0,stream>>>(aa_ei, aa_ei+EP, EP, y2P, saggP);
  k_sag_exp<<<(nP+B-1)/B,B,0,stream>>>(saggP, y2P, pp_brel, enP, zgP, aa_batch, nP);
  k_sag_out<<<(nP*DF+B-1)/B,B,0,stream>>>(AB, enP, zgP, aa_batch, out_aa, nP);
  k_graph_sum<<<NG,B,0,stream>>>(AB, enP, zgP, aa_batch, out_pg, nP);
}

// Round 3
// 2484.414 us; speedup vs baseline: 2.1216x; 1.2923x over previous
//
#include <hip/hip_runtime.h>

#define DF 200   // feature dim D
#define HC 100   // H*C
#define NH 2     // heads
#define CD 50    // channels per head
#define NG 512   // num graphs
#define SCB 256  // scan block

__device__ __forceinline__ float eluf(float x){ return x>0.f ? x : expm1f(x); }

__device__ __forceinline__ void fma4(float4& a, float s, const float4& w){
  a.x += s*w.x; a.y += s*w.y; a.z += s*w.z; a.w += s*w.w;
}

// binary-search node range [start,end) of graph g in sorted batch
__device__ __forceinline__ void seg_range(const int* __restrict__ batch, int N, int g,
                                          int& start, int& end){
  int lo=0, hi=N;
  while(lo<hi){ int m=(lo+hi)>>1; if(batch[m]<g) lo=m+1; else hi=m; }
  start=lo; hi=N;
  while(lo<hi){ int m=(lo+hi)>>1; if(batch[m]<g+1) lo=m+1; else hi=m; }
  end=lo;
}

// ================= CSR build (dst-indexed) =================
__global__ void k_hist(const int* __restrict__ dst, int E, int* __restrict__ deg){
  int e = blockIdx.x*blockDim.x + threadIdx.x;
  if(e<E) atomicAdd(&deg[dst[e]], 1);
}

// in-place exclusive scan step 1: per-block scan (deg -> excl in same array ok), block sums out
__global__ void k_scan1(int* __restrict__ a, int N, int* __restrict__ bsum){
  __shared__ int sh[SCB];
  int t = threadIdx.x, i = blockIdx.x*SCB + t;
  int v = (i<N)? a[i] : 0;
  sh[t] = v; __syncthreads();
  for(int o=1;o<SCB;o<<=1){
    int u = (t>=o)? sh[t-o] : 0; __syncthreads();
    sh[t] += u; __syncthreads();
  }
  if(i<N) a[i] = sh[t]-v;                 // exclusive within block
  if(t==SCB-1) bsum[blockIdx.x] = sh[t];  // block total
}

// step 2: single-block exclusive scan of block sums (nb <= 1024)
__global__ void k_scan2(int* __restrict__ bsum, int nb){
  __shared__ int sh[1024];
  int t = threadIdx.x;
  int v = (t<nb)? bsum[t] : 0;
  sh[t]=v; __syncthreads();
  for(int o=1;o<1024;o<<=1){ int u=(t>=o)?sh[t-o]:0; __syncthreads(); sh[t]+=u; __syncthreads(); }
  if(t<nb) bsum[t] = sh[t]-v;
}

// step 3: add block offsets; mirror into cursor; set rowptr[N]=E
__global__ void k_scan3(int* __restrict__ rowptr, int* __restrict__ cursor,
                        const int* __restrict__ bsum, int N, int E){
  int i = blockIdx.x*SCB + threadIdx.x;
  if(i<N){ int v = rowptr[i] + bsum[blockIdx.x]; rowptr[i]=v; cursor[i]=v; }
  if(blockIdx.x==0 && threadIdx.x==0) rowptr[N]=E;
}

__global__ void k_fill(const int* __restrict__ src, const int* __restrict__ dst, int E,
                       int* __restrict__ cursor, int* __restrict__ csrc){
  int e = blockIdx.x*blockDim.x + threadIdx.x;
  if(e<E){ int p = atomicAdd(&cursor[dst[e]],1); csrc[p] = src[e]; }
}

// ---------------- elementwise elu (f32 -> f32) ----------------
__global__ void k_elu(const float* __restrict__ in, float* __restrict__ out, int n){
  int i = blockIdx.x*blockDim.x + threadIdx.x;
  if(i<n) out[i] = eluf(in[i]);
}

// ---------------- V[k][h] = sum_c W[k][h*50+c]*a[h][c] ----------------
__global__ void k_makeV(const float* __restrict__ W, const float* __restrict__ a, float* __restrict__ V){
  int i = blockIdx.x*blockDim.x + threadIdx.x;
  if(i >= DF*NH) return;
  int k = i>>1, h = i&1;
  float s = 0.f;
  #pragma unroll
  for(int c=0;c<CD;c++) s += W[k*HC + h*CD + c] * a[h*CD + c];
  V[k*2+h] = s;
}

// pack two [200] f32 vectors into V[200][2]
__global__ void k_pack2(const float* __restrict__ a, const float* __restrict__ c, float* __restrict__ V){
  int k = blockIdx.x*blockDim.x + threadIdx.x;
  if(k<DF){ V[k*2] = a[k]; V[k*2+1] = c[k]; }
}

// ---------------- fused 3-pair GEMV ----------------
__global__ void k_gemv3(const float* __restrict__ X,
                        const float* __restrict__ V0, const float* __restrict__ V1, const float* __restrict__ V2,
                        float* __restrict__ o0, float* __restrict__ o1, float* __restrict__ o2, int N){
  int n = blockIdx.x*4 + (threadIdx.x>>6);
  if(n>=N) return;
  int lane = threadIdx.x & 63;
  const float2* xr = (const float2*)(X + (size_t)n*DF);
  float a00=0,a01=0,a10=0,a11=0,a20=0,a21=0;
  for(int k2=lane;k2<DF/2;k2+=64){
    float2 x2 = xr[k2];
    float4 v0 = ((const float4*)V0)[k2];
    float4 v1 = ((const float4*)V1)[k2];
    float4 v2 = ((const float4*)V2)[k2];
    a00 += x2.x*v0.x + x2.y*v0.z;  a01 += x2.x*v0.y + x2.y*v0.w;
    a10 += x2.x*v1.x + x2.y*v1.z;  a11 += x2.x*v1.y + x2.y*v1.w;
    a20 += x2.x*v2.x + x2.y*v2.z;  a21 += x2.x*v2.y + x2.y*v2.w;
  }
  for(int o=32;o;o>>=1){
    a00+=__shfl_down(a00,o); a01+=__shfl_down(a01,o);
    a10+=__shfl_down(a10,o); a11+=__shfl_down(a11,o);
    a20+=__shfl_down(a20,o); a21+=__shfl_down(a21,o);
  }
  if(lane==0){
    o0[n*2]=a00; o0[n*2+1]=a01;
    o1[n*2]=a10; o1[n*2+1]=a11;
    o2[n*2]=a20; o2[n*2+1]=a21;
  }
}

// ---------------- fused 4-pair GEMV ----------------
__global__ void k_gemv4(const float* __restrict__ X,
                        const float* __restrict__ V0, const float* __restrict__ V1,
                        const float* __restrict__ V2, const float* __restrict__ V3,
                        float* __restrict__ o0, float* __restrict__ o1,
                        float* __restrict__ o2, float* __restrict__ o3, int N){
  int n = blockIdx.x*4 + (threadIdx.x>>6);
  if(n>=N) return;
  int lane = threadIdx.x & 63;
  const float2* xr = (const float2*)(X + (size_t)n*DF);
  float a00=0,a01=0,a10=0,a11=0,a20=0,a21=0,a30=0,a31=0;
  for(int k2=lane;k2<DF/2;k2+=64){
    float2 x2 = xr[k2];
    float4 v0 = ((const float4*)V0)[k2];
    float4 v1 = ((const float4*)V1)[k2];
    float4 v2 = ((const float4*)V2)[k2];
    float4 v3 = ((const float4*)V3)[k2];
    a00 += x2.x*v0.x + x2.y*v0.z;  a01 += x2.x*v0.y + x2.y*v0.w;
    a10 += x2.x*v1.x + x2.y*v1.z;  a11 += x2.x*v1.y + x2.y*v1.w;
    a20 += x2.x*v2.x + x2.y*v2.z;  a21 += x2.x*v2.y + x2.y*v2.w;
    a30 += x2.x*v3.x + x2.y*v3.z;  a31 += x2.x*v3.y + x2.y*v3.w;
  }
  for(int o=32;o;o>>=1){
    a00+=__shfl_down(a00,o); a01+=__shfl_down(a01,o);
    a10+=__shfl_down(a10,o); a11+=__shfl_down(a11,o);
    a20+=__shfl_down(a20,o); a21+=__shfl_down(a21,o);
    a30+=__shfl_down(a30,o); a31+=__shfl_down(a31,o);
  }
  if(lane==0){
    o0[n*2]=a00; o0[n*2+1]=a01;
    o1[n*2]=a10; o1[n*2+1]=a11;
    o2[n*2]=a20; o2[n*2+1]=a21;
    o3[n*2]=a30; o3[n*2+1]=a31;
  }
}

// ---------------- GEMM: 4x4 register tile per thread ----------------
__global__ void k_gemm(const float* __restrict__ X, const float* __restrict__ W,
                       float* __restrict__ out, int N){
  int i = blockIdx.x*blockDim.x + threadIdx.x;
  int nq4 = (N+3)>>2;
  if(i >= nq4*25) return;
  int nq = i/25, cg = i%25;
  int n0 = nq*4;
  int r1 = min(n0+1,N-1), r2 = min(n0+2,N-1), r3 = min(n0+3,N-1);
  const float* x0 = X + (size_t)n0*DF;
  const float* x1 = X + (size_t)r1*DF;
  const float* x2 = X + (size_t)r2*DF;
  const float* x3 = X + (size_t)r3*DF;
  const float* wp = W + cg*4;
  float4 a0={0,0,0,0}, a1={0,0,0,0}, a2={0,0,0,0}, a3={0,0,0,0};
  for(int k=0;k<DF;k+=4){
    float4 xa = *(const float4*)(x0 + k);
    float4 xb = *(const float4*)(x1 + k);
    float4 xc = *(const float4*)(x2 + k);
    float4 xd = *(const float4*)(x3 + k);
    float4 w0 = *(const float4*)(wp + (k  )*HC);
    float4 w1 = *(const float4*)(wp + (k+1)*HC);
    float4 w2 = *(const float4*)(wp + (k+2)*HC);
    float4 w3 = *(const float4*)(wp + (k+3)*HC);
    fma4(a0,xa.x,w0); fma4(a0,xa.y,w1); fma4(a0,xa.z,w2); fma4(a0,xa.w,w3);
    fma4(a1,xb.x,w0); fma4(a1,xb.y,w1); fma4(a1,xb.z,w2); fma4(a1,xb.w,w3);
    fma4(a2,xc.x,w0); fma4(a2,xc.y,w1); fma4(a2,xc.z,w2); fma4(a2,xc.w,w3);
    fma4(a3,xd.x,w0); fma4(a3,xd.y,w1); fma4(a3,xd.z,w2); fma4(a3,xd.w,w3);
  }
  float* o = out + (size_t)n0*HC + cg*4;
  *(float4*)(o) = a0;
  if(n0+1<N) *(float4*)(o+HC)   = a1;
  if(n0+2<N) *(float4*)(o+2*HC) = a2;
  if(n0+3<N) *(float4*)(o+3*HC) = a3;
}

// ---------------- fused dual GEMM: out1 = X@W1, out2 = X@W2 ----------------
__global__ void k_gemm2(const float* __restrict__ X,
                        const float* __restrict__ W1, const float* __restrict__ W2,
                        float* __restrict__ out1, float* __restrict__ out2, int N){
  int i = blockIdx.x*blockDim.x + threadIdx.x;
  int nq4 = (N+3)>>2;
  if(i >= nq4*25) return;
  int nq = i/25, cg = i%25;
  int n0 = nq*4;
  int r1 = min(n0+1,N-1), r2 = min(n0+2,N-1), r3 = min(n0+3,N-1);
  const float* x0 = X + (size_t)n0*DF;
  const float* x1 = X + (size_t)r1*DF;
  const float* x2 = X + (size_t)r2*DF;
  const float* x3 = X + (size_t)r3*DF;
  const float* wp1 = W1 + cg*4;
  const float* wp2 = W2 + cg*4;
  float4 a0={0,0,0,0}, a1={0,0,0,0}, a2={0,0,0,0}, a3={0,0,0,0};
  float4 b0={0,0,0,0}, b1={0,0,0,0}, b2={0,0,0,0}, b3={0,0,0,0};
  for(int k=0;k<DF;k+=4){
    float4 xa = *(const float4*)(x0 + k);
    float4 xb = *(const float4*)(x1 + k);
    float4 xc = *(const float4*)(x2 + k);
    float4 xd = *(const float4*)(x3 + k);
    float4 u0 = *(const float4*)(wp1 + (k  )*HC);
    float4 u1 = *(const float4*)(wp1 + (k+1)*HC);
    float4 u2 = *(const float4*)(wp1 + (k+2)*HC);
    float4 u3 = *(const float4*)(wp1 + (k+3)*HC);
    float4 v0 = *(const float4*)(wp2 + (k  )*HC);
    float4 v1 = *(const float4*)(wp2 + (k+1)*HC);
    float4 v2 = *(const float4*)(wp2 + (k+2)*HC);
    float4 v3 = *(const float4*)(wp2 + (k+3)*HC);
    fma4(a0,xa.x,u0); fma4(a0,xa.y,u1); fma4(a0,xa.z,u2); fma4(a0,xa.w,u3);
    fma4(a1,xb.x,u0); fma4(a1,xb.y,u1); fma4(a1,xb.z,u2); fma4(a1,xb.w,u3);
    fma4(a2,xc.x,u0); fma4(a2,xc.y,u1); fma4(a2,xc.z,u2); fma4(a2,xc.w,u3);
    fma4(a3,xd.x,u0); fma4(a3,xd.y,u1); fma4(a3,xd.z,u2); fma4(a3,xd.w,u3);
    fma4(b0,xa.x,v0); fma4(b0,xa.y,v1); fma4(b0,xa.z,v2); fma4(b0,xa.w,v3);
    fma4(b1,xb.x,v0); fma4(b1,xb.y,v1); fma4(b1,xb.z,v2); fma4(b1,xb.w,v3);
    fma4(b2,xc.x,v0); fma4(b2,xc.y,v1); fma4(b2,xc.z,v2); fma4(b2,xc.w,v3);
    fma4(b3,xd.x,v0); fma4(b3,xd.y,v1); fma4(b3,xd.z,v2); fma4(b3,xd.w,v3);
  }
  float* o1 = out1 + (size_t)n0*HC + cg*4;
  float* o2 = out2 + (size_t)n0*HC + cg*4;
  *(float4*)(o1) = a0;
  *(float4*)(o2) = b0;
  if(n0+1<N){ *(float4*)(o1+HC)   = a1; *(float4*)(o2+HC)   = b1; }
  if(n0+2<N){ *(float4*)(o1+2*HC) = a2; *(float4*)(o2+2*HC) = b2; }
  if(n0+3<N){ *(float4*)(o1+3*HC) = a3; *(float4*)(o2+3*HC) = b3; }
}

// ---------------- GAT gather: one block (128 thr) per dst node ----------------
// cat[n,colOff+f] = (sum_{s in in(n)} ev(s,n)*hs[s,f]) / (z+1e-16) + bias[f]
// self-loop (s=n) included iff n<nloop. z identical in all lanes (no reduce needed).
__global__ void k_gat_gather(const int* __restrict__ rowptr, const int* __restrict__ csrc,
                             const float* __restrict__ hs,
                             const float* __restrict__ als, const float* __restrict__ ald,
                             const float* __restrict__ bias,
                             float* __restrict__ cat, int colOff, int nloop, int N){
  int n = blockIdx.x; if(n>=N) return;
  int f = threadIdx.x; if(f>=HC) return;
  int h = f/CD;
  float aldh = ald[n*2+h];
  float bi_f = bias[f];
  float acc = 0.f, z = 0.f;
  int e = rowptr[n], e1 = rowptr[n+1];
  for(; e<e1; e++){
    int s = csrc[e];
    float lg = als[s*2+h] + aldh;
    lg = lg>0.f ? lg : 0.2f*lg;
    float ev = __expf(lg);
    z += ev;
    acc += ev*hs[(size_t)s*HC+f];
  }
  if(n<nloop){
    float lg = als[n*2+h] + aldh;
    lg = lg>0.f ? lg : 0.2f*lg;
    float ev = __expf(lg);
    z += ev;
    acc += ev*hs[(size_t)n*HC+f];
  }
  cat[(size_t)n*DF + colOff + f] = acc/(z+1e-16f) + bi_f;
}

// ---------------- graph-LN stats only (cat already finalized), one block per graph ----------------
__global__ void k_ln_stats2(const float* __restrict__ cat, const int* __restrict__ batch,
                            float* __restrict__ gs, float* __restrict__ gq, float* __restrict__ gc, int N){
  int g = blockIdx.x, start, end;
  seg_range(batch, N, g, start, end);
  const float4* c4 = (const float4*)cat;
  int i0 = start*(DF/4), i1 = end*(DF/4);
  float s=0.f, q=0.f;
  for(int i=i0+threadIdx.x; i<i1; i+=blockDim.x){
    float4 v = c4[i];
    s += v.x+v.y+v.z+v.w;
    q += v.x*v.x+v.y*v.y+v.z*v.z+v.w*v.w;
  }
  for(int o=32;o;o>>=1){ s+=__shfl_down(s,o); q+=__shfl_down(q,o); }
  __shared__ float ss[8], sq[8];
  int wv = threadIdx.x>>6;
  if((threadIdx.x&63)==0){ ss[wv]=s; sq[wv]=q; }
  __syncthreads();
  if(threadIdx.x==0){
    float S=0.f, Q=0.f;
    int nw = blockDim.x>>6;
    for(int k=0;k<nw;k++){ S+=ss[k]; Q+=sq[k]; }
    gs[g]=S; gq[g]=Q; gc[g]=(float)(end-start);
  }
}

// ---------------- fused: graph-LN normalize + elu (in place) + up to 2 attention GEMV pairs ----------------
__global__ void k_ln_norm_f(float* __restrict__ x, const int* __restrict__ batch,
                            const float* __restrict__ gs, const float* __restrict__ gq, const float* __restrict__ gc,
                            const float* __restrict__ wv, const float* __restrict__ bv,
                            const float* __restrict__ V0, float* __restrict__ o0,
                            const float* __restrict__ V1, float* __restrict__ o1, int N){
  int n = blockIdx.x*4 + (threadIdx.x>>6);
  if(n>=N) return;
  int lane = threadIdx.x & 63;
  int g = batch[n];
  float norm = fmaxf(gc[g],1.f)*(float)DF;
  float mean = gs[g]/norm;
  float var  = fmaxf(gq[g]/norm - mean*mean, 0.f);
  float rs   = rsqrtf(var+1e-5f);
  float2* xr = (float2*)(x + (size_t)n*DF);
  float a00=0,a01=0,a10=0,a11=0;
  for(int k2=lane;k2<DF/2;k2+=64){
    float2 x2 = xr[k2];
    float2 w2 = ((const float2*)wv)[k2];
    float2 b2 = ((const float2*)bv)[k2];
    float v0 = eluf((x2.x-mean)*rs*w2.x + b2.x);
    float v1 = eluf((x2.y-mean)*rs*w2.y + b2.y);
    xr[k2] = make_float2(v0,v1);
    float4 vv = ((const float4*)V0)[k2];
    a00 += v0*vv.x + v1*vv.z;  a01 += v0*vv.y + v1*vv.w;
    if(V1){
      float4 u = ((const float4*)V1)[k2];
      a10 += v0*u.x + v1*u.z;  a11 += v0*u.y + v1*u.w;
    }
  }
  for(int o=32;o;o>>=1){
    a00+=__shfl_down(a00,o); a01+=__shfl_down(a01,o);
    a10+=__shfl_down(a10,o); a11+=__shfl_down(a11,o);
  }
  if(lane==0){
    o0[n*2]=a00; o0[n*2+1]=a01;
    if(o1){ o1[n*2]=a10; o1[n*2+1]=a11; }
  }
}

// ---------------- SAG: sagg[n] = sum over in-edges of y2[src] (gather, no atomics) ----------------
__global__ void k_sag_gather(const int* __restrict__ rowptr, const int* __restrict__ csrc,
                             const float* __restrict__ y2, float* __restrict__ sagg, int N){
  int n = blockIdx.x*blockDim.x + threadIdx.x;
  if(n>=N) return;
  float s=0.f;
  int e1 = rowptr[n+1];
  for(int e=rowptr[n]; e<e1; e++) s += y2[csrc[e]*2];
  sagg[n] = s;
}

// ---------------- SAG: en[n]=exp(score); zg[g]+=en ----------------
__global__ void k_sag_exp(const float* __restrict__ sagg, const float* __restrict__ y2,
                          const float* __restrict__ brel,
                          float* __restrict__ en, float* __restrict__ zg,
                          const int* __restrict__ batch, int N){
  int n = blockIdx.x*blockDim.x + threadIdx.x;
  if(n>=N) return;
  float sc = sagg[n] + brel[0] + y2[n*2+1];
  float e = __expf(sc);
  en[n] = e;
  atomicAdd(&zg[batch[n]], e);
}

// ---------------- SAG: out = x * alpha ----------------
__global__ void k_sag_out(const float* __restrict__ x, const float* __restrict__ en,
                          const float* __restrict__ zg, const int* __restrict__ batch,
                          float* __restrict__ out, int N){
  int i = blockIdx.x*blockDim.x + threadIdx.x;
  if(i>=N*DF) return;
  int n = i/DF;
  float a = en[n]/(zg[batch[n]]+1e-16f);
  out[i] = x[i]*a;
}

// ---------------- per-graph readout ----------------
__global__ void k_graph_sum(const float* __restrict__ x, const float* __restrict__ en,
                            const float* __restrict__ zg, const int* __restrict__ batch,
                            float* __restrict__ outg, int N){
  int g = blockIdx.x, start, end;
  seg_range(batch, N, g, start, end);
  int f = threadIdx.x;
  if(f>=DF) return;
  float s = 0.f;
  int n = start;
  for(; n+4<=end; n+=4){
    s += x[(size_t) n   *DF+f]*en[n]
       + x[(size_t)(n+1)*DF+f]*en[n+1]
       + x[(size_t)(n+2)*DF+f]*en[n+2]
       + x[(size_t)(n+3)*DF+f]*en[n+3];
  }
  for(; n<end; n++) s += x[(size_t)n*DF+f]*en[n];
  outg[(size_t)g*DF+f] = s/(zg[g]+1e-16f);
}

extern "C" void kernel_launch(void* const* d_in, const int* in_sizes, int n_in,
                              void* d_out, int out_size, void* d_ws, size_t ws_size,
                              hipStream_t stream){
  const float* atom_x    = (const float*)d_in[0];
  const int*   atom_ei   = (const int*)  d_in[1];
  const int*   atom_batch= (const int*)  d_in[2];
  const float* aa_x      = (const float*)d_in[3];
  const int*   aa_ei     = (const int*)  d_in[4];
  /* d_in[5] aa_edge_attr: ignored (GATConv has no edge_dim) */
  const int*   aa_batch  = (const int*)  d_in[6];
  const int*   m2p       = (const int*)  d_in[7];
  const float* Wd     =(const float*)d_in[8];
  const float* ad_src =(const float*)d_in[9];
  const float* ad_dst =(const float*)d_in[10];
  const float* bd     =(const float*)d_in[11];
  const float* Wp     =(const float*)d_in[12];
  const float* ap_src =(const float*)d_in[13];
  const float* ap_dst =(const float*)d_in[14];
  const float* bp     =(const float*)d_in[15];
  const float* Wi_src =(const float*)d_in[16];
  const float* Wi_dst =(const float*)d_in[17];
  const float* ai_src =(const float*)d_in[18];
  const float* ai_dst =(const float*)d_in[19];
  const float* bi     =(const float*)d_in[20];
  const float* ln_d_w =(const float*)d_in[21];
  const float* ln_d_b =(const float*)d_in[22];
  const float* ln_p_w =(const float*)d_in[23];
  const float* ln_p_b =(const float*)d_in[24];
  const float* pd_Wrel=(const float*)d_in[25];
  const float* pd_brel=(const float*)d_in[26];
  const float* pd_Wroot=(const float*)d_in[27];
  const float* pp_Wrel=(const float*)d_in[28];
  const float* pp_brel=(const float*)d_in[29];
  const float* pp_Wroot=(const float*)d_in[30];

  const int nA = in_sizes[0]/DF;     // 25600 atoms
  const int EA = in_sizes[1]/2;      // 102400 atom edges
  const int nP = in_sizes[3]/DF;     // 204800 aa nodes
  const int EP = in_sizes[4]/2;      // 1024000 aa edges
  const int EM = in_sizes[7]/2;      // 512000 m2p edges
  const int nLoop = nA<nP ? nA : nP;

  float* w = (float*)d_ws;
  size_t off = 0;
  auto alloc = [&](size_t n){ float* p = w+off; off += (n+63)&~(size_t)63; return p; };

  float* AX  = alloc((size_t)nA*DF);   // elu(atom_x) -> atom_cat -> atom_h
  float* AB  = alloc((size_t)nP*DF);   // elu(aa_x)   -> aa_cat   -> aa_h
  float* H1  = alloc((size_t)nA*HC);   // h1 (atom@Wd), later hs4 (atom_h@Wi_src)
  float* HS2 = alloc((size_t)nP*HC);   // aa@Wi_src
  float* H3  = alloc((size_t)nP*HC);   // aa@Wp
  float* als1=alloc((size_t)nA*2); float* ald1=alloc((size_t)nA*2);
  float* als2=alloc((size_t)nP*2); float* ald2=alloc((size_t)nA*2);
  float* als3=alloc((size_t)nP*2); float* ald3=alloc((size_t)nP*2);
  float* als4=alloc((size_t)nA*2); float* ald4=alloc((size_t)nP*2);
  float* Vds=alloc(DF*2); float* Vdd=alloc(DF*2);
  float* Vps=alloc(DF*2); float* Vpd=alloc(DF*2);
  float* Vis=alloc(DF*2); float* Vid=alloc(DF*2);
  float* VsA=alloc(DF*2); float* VsP=alloc(DF*2);
  float* y2A=alloc((size_t)nA*2); float* y2P=alloc((size_t)nP*2);
  float* enA=alloc(nA);   float* enP=alloc(nP);
  float* gsA=alloc(NG); float* gqA=alloc(NG); float* gcA=alloc(NG);
  float* gsP=alloc(NG); float* gqP=alloc(NG); float* gcP=alloc(NG);
  float* saggA=alloc(nA); float* saggP=alloc(nP);
  // CSR arrays (int, stored in float slots)
  int* srcAi = (int*)alloc(EA);         // atom-intra src list
  int* srcAm = (int*)alloc(EM);         // m2p->atom src list (aa ids)
  int* srcPi = (int*)alloc(EP);         // aa-intra src list
  int* srcPm = (int*)alloc(EM);         // m2p->aa src list (atom ids)
  int* curAi = (int*)alloc(nA); int* curAm = (int*)alloc(nA);
  int* curPi = (int*)alloc(nP); int* curPm = (int*)alloc(nP);
  int* bsum  = (int*)alloc(1024);
  // ---- contiguous zero region: rowptrs (hist accumulators) + zg ----
  float* zr0 = w+off;
  int* rpAi = (int*)alloc(nA+1); int* rpAm = (int*)alloc(nA+1);
  int* rpPi = (int*)alloc(nP+1); int* rpPm = (int*)alloc(nP+1);
  float* zgA=alloc(NG); float* zgP=alloc(NG);
  size_t zrBytes = ((w+off) - zr0)*sizeof(float);
  if(off*sizeof(float) > ws_size) return; // workspace too small — bail

  float* out_atom = (float*)d_out;
  float* out_aa   = out_atom + (size_t)nA*DF;
  float* out_dg   = out_aa   + (size_t)nP*DF;
  float* out_pg   = out_dg   + (size_t)NG*DF;

  const int B = 256;
  hipMemsetAsync(zr0, 0, zrBytes, stream);

  // ---- CSR builds (4 edge sets, dst-indexed; store src directly) ----
  auto buildCSR = [&](const int* esrc, const int* edst, int E, int N,
                      int* rowptr, int* cursor, int* csrc){
    int nb = (N+SCB-1)/SCB;
    k_hist <<<(E+B-1)/B, B, 0, stream>>>(edst, E, rowptr);
    k_scan1<<<nb, SCB, 0, stream>>>(rowptr, N, bsum);
    k_scan2<<<1, 1024, 0, stream>>>(bsum, nb);
    k_scan3<<<nb, SCB, 0, stream>>>(rowptr, cursor, bsum, N, E);
    k_fill <<<(E+B-1)/B, B, 0, stream>>>(esrc, edst, E, cursor, csrc);
  };
  buildCSR(atom_ei,      atom_ei+EA, EA, nA, rpAi, curAi, srcAi);  // atom intra
  buildCSR(m2p+EM,       m2p,        EM, nA, rpAm, curAm, srcAm);  // m2p -> atom (src=aa)
  buildCSR(aa_ei,        aa_ei+EP,   EP, nP, rpPi, curPi, srcPi);  // aa intra
  buildCSR(m2p,          m2p+EM,     EM, nP, rpPm, curPm, srcPm);  // m2p -> aa (src=atom)

  // 1. elu
  k_elu<<<(nA*DF+B-1)/B, B, 0, stream>>>(atom_x, AX, nA*DF);
  k_elu<<<(nP*DF+B-1)/B, B, 0, stream>>>(aa_x,   AB, nP*DF);

  // 2. fused attention vectors
  k_makeV<<<2,B,0,stream>>>(Wd,     ad_src, Vds);
  k_makeV<<<2,B,0,stream>>>(Wd,     ad_dst, Vdd);
  k_makeV<<<2,B,0,stream>>>(Wp,     ap_src, Vps);
  k_makeV<<<2,B,0,stream>>>(Wp,     ap_dst, Vpd);
  k_makeV<<<2,B,0,stream>>>(Wi_src, ai_src, Vis);
  k_makeV<<<2,B,0,stream>>>(Wi_dst, ai_dst, Vid);
  k_pack2<<<1,B,0,stream>>>(pd_Wrel, pd_Wroot, VsA);
  k_pack2<<<1,B,0,stream>>>(pp_Wrel, pp_Wroot, VsP);

  // 3. GEMMs + fused attention GEMVs (consume elu buffers)
  { int tot = ((nA+3)/4)*25;
    k_gemm<<<(tot+B-1)/B, B, 0, stream>>>(AX, Wd, H1, nA); }
  { int tot = ((nP+3)/4)*25;
    k_gemm2<<<(tot+B-1)/B, B, 0, stream>>>(AB, Wi_src, Wp, HS2, H3, nP); }
  k_gemv3<<<(nA+3)/4,B,0,stream>>>(AX, Vds, Vdd, Vid, als1, ald1, ald2, nA);
  k_gemv4<<<(nP+3)/4,B,0,stream>>>(AB, Vis, Vps, Vpd, Vid, als2, als3, ald3, ald4, nP);

  // 4. GAT gathers (overwrite AX/AB; softmax denom + bias fused; no atomics, no memset)
  k_gat_gather<<<nA,128,0,stream>>>(rpAi, srcAi, H1,  als1, ald1, bd, AX, 0,  nA,    nA);
  k_gat_gather<<<nA,128,0,stream>>>(rpAm, srcAm, HS2, als2, ald2, bi, AX, HC, nLoop, nA);
  k_gat_gather<<<nP,128,0,stream>>>(rpPi, srcPi, H3,  als3, ald3, bp, AB, 0,  nP,    nP);

  // 5. atom: LN stats + fused norm/elu/GEMVs
  k_ln_stats2<<<NG,512,0,stream>>>(AX, atom_batch, gsA, gqA, gcA, nA);
  k_ln_norm_f<<<(nA+3)/4,B,0,stream>>>(AX, atom_batch, gsA, gqA, gcA, ln_d_w, ln_d_b,
                                       Vis, als4, VsA, y2A, nA);

  // 6. hs4 = atom_h @ Wi_src (reuse H1); GAT4 gather
  { int tot = ((nA+3)/4)*25;
    k_gemm<<<(tot+B-1)/B, B, 0, stream>>>(AX, Wi_src, H1, nA); }
  k_gat_gather<<<nP,128,0,stream>>>(rpPm, srcPm, H1, als4, ald4, bi, AB, HC, nLoop, nP);

  // 7. aa: LN stats + fused norm/elu/y2 GEMV
  k_ln_stats2<<<NG,512,0,stream>>>(AB, aa_batch, gsP, gqP, gcP, nP);
  k_ln_norm_f<<<(nP+3)/4,B,0,stream>>>(AB, aa_batch, gsP, gqP, gcP, ln_p_w, ln_p_b,
                                       VsP, y2P, (const float*)nullptr, (float*)nullptr, nP);

  // 8. SAG pool atom + readout
  k_sag_gather<<<(nA+B-1)/B,B,0,stream>>>(rpAi, srcAi, y2A, saggA, nA);
  k_sag_exp<<<(nA+B-1)/B,B,0,stream>>>(saggA, y2A, pd_brel, enA, zgA, atom_batch, nA);
  k_sag_out<<<(nA*DF+B-1)/B,B,0,stream>>>(AX, enA, zgA, atom_batch, out_atom, nA);
  k_graph_sum<<<NG,B,0,stream>>>(AX, enA, zgA, atom_batch, out_dg, nA);

  // 9. SAG pool aa + readout
  k_sag_gather<<<(nP+B-1)/B,B,0,stream>>>(rpPi, srcPi, y2P, saggP, nP);
  k_sag_exp<<<(nP+B-1)/B,B,0,stream>>>(saggP, y2P, pp_brel, enP, zgP, aa_batch, nP);
  k_sag_out<<<(nP*DF+B-1)/B,B,0,stream>>>(AB, enP, zgP, aa_batch, out_aa, nP);
  k_graph_sum<<<NG,B,0,stream>>>(AB, enP, zgP, aa_batch, out_pg, nP);
}

// Round 4
// 2139.484 us; speedup vs baseline: 2.4636x; 1.1612x over previous
//
#include <hip/hip_runtime.h>

#define DF 200   // feature dim D
#define HC 100   // H*C
#define NH 2     // heads
#define CD 50    // channels per head
#define NG 512   // num graphs
#define SCB 256  // scan block
#define TM 40    // GEMM node-tile (rows per block)
#define XLD (DF+4)  // padded LDS row stride (204 floats, 16B-aligned, bank-spread)

__device__ __forceinline__ float eluf(float x){ return x>0.f ? x : expm1f(x); }

__device__ __forceinline__ void fma4(float4& a, float s, const float4& w){
  a.x += s*w.x; a.y += s*w.y; a.z += s*w.z; a.w += s*w.w;
}

// binary-search node range [start,end) of graph g in sorted batch
__device__ __forceinline__ void seg_range(const int* __restrict__ batch, int N, int g,
                                          int& start, int& end){
  int lo=0, hi=N;
  while(lo<hi){ int m=(lo+hi)>>1; if(batch[m]<g) lo=m+1; else hi=m; }
  start=lo; hi=N;
  while(lo<hi){ int m=(lo+hi)>>1; if(batch[m]<g+1) lo=m+1; else hi=m; }
  end=lo;
}

// ================= CSR build (dst-indexed) =================
__global__ void k_hist(const int* __restrict__ dst, int E, int* __restrict__ deg){
  int e = blockIdx.x*blockDim.x + threadIdx.x;
  if(e<E) atomicAdd(&deg[dst[e]], 1);
}

__global__ void k_scan1(int* __restrict__ a, int N, int* __restrict__ bsum){
  __shared__ int sh[SCB];
  int t = threadIdx.x, i = blockIdx.x*SCB + t;
  int v = (i<N)? a[i] : 0;
  sh[t] = v; __syncthreads();
  for(int o=1;o<SCB;o<<=1){
    int u = (t>=o)? sh[t-o] : 0; __syncthreads();
    sh[t] += u; __syncthreads();
  }
  if(i<N) a[i] = sh[t]-v;                 // exclusive within block
  if(t==SCB-1) bsum[blockIdx.x] = sh[t];  // block total
}

__global__ void k_scan2(int* __restrict__ bsum, int nb){
  __shared__ int sh[1024];
  int t = threadIdx.x;
  int v = (t<nb)? bsum[t] : 0;
  sh[t]=v; __syncthreads();
  for(int o=1;o<1024;o<<=1){ int u=(t>=o)?sh[t-o]:0; __syncthreads(); sh[t]+=u; __syncthreads(); }
  if(t<nb) bsum[t] = sh[t]-v;
}

__global__ void k_scan3(int* __restrict__ rowptr, int* __restrict__ cursor,
                        const int* __restrict__ bsum, int N, int E){
  int i = blockIdx.x*SCB + threadIdx.x;
  if(i<N){ int v = rowptr[i] + bsum[blockIdx.x]; rowptr[i]=v; cursor[i]=v; }
  if(blockIdx.x==0 && threadIdx.x==0) rowptr[N]=E;
}

__global__ void k_fill(const int* __restrict__ src, const int* __restrict__ dst, int E,
                       int* __restrict__ cursor, int* __restrict__ csrc){
  int e = blockIdx.x*blockDim.x + threadIdx.x;
  if(e<E){ int p = atomicAdd(&cursor[dst[e]],1); csrc[p] = src[e]; }
}

// ---------------- V[k][h] = sum_c W[k][h*50+c]*a[h][c] ----------------
__global__ void k_makeV(const float* __restrict__ W, const float* __restrict__ a, float* __restrict__ V){
  int i = blockIdx.x*blockDim.x + threadIdx.x;
  if(i >= DF*NH) return;
  int k = i>>1, h = i&1;
  float s = 0.f;
  #pragma unroll
  for(int c=0;c<CD;c++) s += W[k*HC + h*CD + c] * a[h*CD + c];
  V[k*2+h] = s;
}

// pack two [200] f32 vectors into V[200][2]
__global__ void k_pack2(const float* __restrict__ a, const float* __restrict__ c, float* __restrict__ V){
  int k = blockIdx.x*blockDim.x + threadIdx.x;
  if(k<DF){ V[k*2] = a[k]; V[k*2+1] = c[k]; }
}

// ---------------- fused 3-pair GEMV (elu applied to X inline) ----------------
__global__ void k_gemv3(const float* __restrict__ X,
                        const float* __restrict__ V0, const float* __restrict__ V1, const float* __restrict__ V2,
                        float* __restrict__ o0, float* __restrict__ o1, float* __restrict__ o2, int N){
  int n = blockIdx.x*4 + (threadIdx.x>>6);
  if(n>=N) return;
  int lane = threadIdx.x & 63;
  const float2* xr = (const float2*)(X + (size_t)n*DF);
  float a00=0,a01=0,a10=0,a11=0,a20=0,a21=0;
  for(int k2=lane;k2<DF/2;k2+=64){
    float2 x2 = xr[k2];
    x2.x = eluf(x2.x); x2.y = eluf(x2.y);
    float4 v0 = ((const float4*)V0)[k2];
    float4 v1 = ((const float4*)V1)[k2];
    float4 v2 = ((const float4*)V2)[k2];
    a00 += x2.x*v0.x + x2.y*v0.z;  a01 += x2.x*v0.y + x2.y*v0.w;
    a10 += x2.x*v1.x + x2.y*v1.z;  a11 += x2.x*v1.y + x2.y*v1.w;
    a20 += x2.x*v2.x + x2.y*v2.z;  a21 += x2.x*v2.y + x2.y*v2.w;
  }
  for(int o=32;o;o>>=1){
    a00+=__shfl_down(a00,o); a01+=__shfl_down(a01,o);
    a10+=__shfl_down(a10,o); a11+=__shfl_down(a11,o);
    a20+=__shfl_down(a20,o); a21+=__shfl_down(a21,o);
  }
  if(lane==0){
    o0[n*2]=a00; o0[n*2+1]=a01;
    o1[n*2]=a10; o1[n*2+1]=a11;
    o2[n*2]=a20; o2[n*2+1]=a21;
  }
}

// ---------------- fused 4-pair GEMV (elu applied to X inline) ----------------
__global__ void k_gemv4(const float* __restrict__ X,
                        const float* __restrict__ V0, const float* __restrict__ V1,
                        const float* __restrict__ V2, const float* __restrict__ V3,
                        float* __restrict__ o0, float* __restrict__ o1,
                        float* __restrict__ o2, float* __restrict__ o3, int N){
  int n = blockIdx.x*4 + (threadIdx.x>>6);
  if(n>=N) return;
  int lane = threadIdx.x & 63;
  const float2* xr = (const float2*)(X + (size_t)n*DF);
  float a00=0,a01=0,a10=0,a11=0,a20=0,a21=0,a30=0,a31=0;
  for(int k2=lane;k2<DF/2;k2+=64){
    float2 x2 = xr[k2];
    x2.x = eluf(x2.x); x2.y = eluf(x2.y);
    float4 v0 = ((const float4*)V0)[k2];
    float4 v1 = ((const float4*)V1)[k2];
    float4 v2 = ((const float4*)V2)[k2];
    float4 v3 = ((const float4*)V3)[k2];
    a00 += x2.x*v0.x + x2.y*v0.z;  a01 += x2.x*v0.y + x2.y*v0.w;
    a10 += x2.x*v1.x + x2.y*v1.z;  a11 += x2.x*v1.y + x2.y*v1.w;
    a20 += x2.x*v2.x + x2.y*v2.z;  a21 += x2.x*v2.y + x2.y*v2.w;
    a30 += x2.x*v3.x + x2.y*v3.z;  a31 += x2.x*v3.y + x2.y*v3.w;
  }
  for(int o=32;o;o>>=1){
    a00+=__shfl_down(a00,o); a01+=__shfl_down(a01,o);
    a10+=__shfl_down(a10,o); a11+=__shfl_down(a11,o);
    a20+=__shfl_down(a20,o); a21+=__shfl_down(a21,o);
    a30+=__shfl_down(a30,o); a31+=__shfl_down(a31,o);
  }
  if(lane==0){
    o0[n*2]=a00; o0[n*2+1]=a01;
    o1[n*2]=a10; o1[n*2+1]=a11;
    o2[n*2]=a20; o2[n*2+1]=a21;
    o3[n*2]=a30; o3[n*2+1]=a31;
  }
}

// ---------------- LDS-tiled GEMM: out[N,100] = act(X)[N,200] @ W[200,100] ----------------
// Block = 40-node tile staged in LDS once; 250 threads = 10 node-quads x 25 colgroups,
// each computes a 4x4 register tile. X global traffic drops 25x vs untiled.
template<int ELU>
__global__ __launch_bounds__(256) void k_gemm_t(const float* __restrict__ X, const float* __restrict__ W,
                                                float* __restrict__ out, int N){
  __shared__ float xs[TM*XLD];
  int bm = blockIdx.x*TM;
  int rows = min(TM, N-bm);
  for(int idx = threadIdx.x; idx < rows*(DF/4); idx += blockDim.x){
    int r = idx/(DF/4), c = idx%(DF/4);
    float4 v = *(const float4*)(X + (size_t)(bm+r)*DF + c*4);
    if(ELU){ v.x=eluf(v.x); v.y=eluf(v.y); v.z=eluf(v.z); v.w=eluf(v.w); }
    *(float4*)(&xs[r*XLD + c*4]) = v;
  }
  __syncthreads();
  int i = threadIdx.x;
  if(i >= 250) return;
  int nq = i/25, cg = i%25;
  int n0 = nq*4;
  if(n0 >= rows) return;
  int r1 = min(n0+1,rows-1), r2 = min(n0+2,rows-1), r3 = min(n0+3,rows-1);
  const float* x0 = xs + n0*XLD;
  const float* x1 = xs + r1*XLD;
  const float* x2 = xs + r2*XLD;
  const float* x3 = xs + r3*XLD;
  const float* wp = W + cg*4;
  float4 a0={0,0,0,0}, a1={0,0,0,0}, a2={0,0,0,0}, a3={0,0,0,0};
  for(int k=0;k<DF;k+=4){
    float4 xa = *(const float4*)(x0 + k);
    float4 xb = *(const float4*)(x1 + k);
    float4 xc = *(const float4*)(x2 + k);
    float4 xd = *(const float4*)(x3 + k);
    float4 w0 = *(const float4*)(wp + (k  )*HC);
    float4 w1 = *(const float4*)(wp + (k+1)*HC);
    float4 w2 = *(const float4*)(wp + (k+2)*HC);
    float4 w3 = *(const float4*)(wp + (k+3)*HC);
    fma4(a0,xa.x,w0); fma4(a0,xa.y,w1); fma4(a0,xa.z,w2); fma4(a0,xa.w,w3);
    fma4(a1,xb.x,w0); fma4(a1,xb.y,w1); fma4(a1,xb.z,w2); fma4(a1,xb.w,w3);
    fma4(a2,xc.x,w0); fma4(a2,xc.y,w1); fma4(a2,xc.z,w2); fma4(a2,xc.w,w3);
    fma4(a3,xd.x,w0); fma4(a3,xd.y,w1); fma4(a3,xd.z,w2); fma4(a3,xd.w,w3);
  }
  float* o = out + (size_t)(bm+n0)*HC + cg*4;
  *(float4*)(o) = a0;
  if(n0+1<rows) *(float4*)(o+HC)   = a1;
  if(n0+2<rows) *(float4*)(o+2*HC) = a2;
  if(n0+3<rows) *(float4*)(o+3*HC) = a3;
}

// ---------------- LDS-tiled dual GEMM: out1 = act(X)@W1, out2 = act(X)@W2 ----------------
template<int ELU>
__global__ __launch_bounds__(256) void k_gemm2_t(const float* __restrict__ X,
                        const float* __restrict__ W1, const float* __restrict__ W2,
                        float* __restrict__ out1, float* __restrict__ out2, int N){
  __shared__ float xs[TM*XLD];
  int bm = blockIdx.x*TM;
  int rows = min(TM, N-bm);
  for(int idx = threadIdx.x; idx < rows*(DF/4); idx += blockDim.x){
    int r = idx/(DF/4), c = idx%(DF/4);
    float4 v = *(const float4*)(X + (size_t)(bm+r)*DF + c*4);
    if(ELU){ v.x=eluf(v.x); v.y=eluf(v.y); v.z=eluf(v.z); v.w=eluf(v.w); }
    *(float4*)(&xs[r*XLD + c*4]) = v;
  }
  __syncthreads();
  int i = threadIdx.x;
  if(i >= 250) return;
  int nq = i/25, cg = i%25;
  int n0 = nq*4;
  if(n0 >= rows) return;
  int r1 = min(n0+1,rows-1), r2 = min(n0+2,rows-1), r3 = min(n0+3,rows-1);
  const float* x0 = xs + n0*XLD;
  const float* x1 = xs + r1*XLD;
  const float* x2 = xs + r2*XLD;
  const float* x3 = xs + r3*XLD;
  const float* wp1 = W1 + cg*4;
  const float* wp2 = W2 + cg*4;
  float4 a0={0,0,0,0}, a1={0,0,0,0}, a2={0,0,0,0}, a3={0,0,0,0};
  float4 b0={0,0,0,0}, b1={0,0,0,0}, b2={0,0,0,0}, b3={0,0,0,0};
  for(int k=0;k<DF;k+=4){
    float4 xa = *(const float4*)(x0 + k);
    float4 xb = *(const float4*)(x1 + k);
    float4 xc = *(const float4*)(x2 + k);
    float4 xd = *(const float4*)(x3 + k);
    float4 u0 = *(const float4*)(wp1 + (k  )*HC);
    float4 u1 = *(const float4*)(wp1 + (k+1)*HC);
    float4 u2 = *(const float4*)(wp1 + (k+2)*HC);
    float4 u3 = *(const float4*)(wp1 + (k+3)*HC);
    float4 v0 = *(const float4*)(wp2 + (k  )*HC);
    float4 v1 = *(const float4*)(wp2 + (k+1)*HC);
    float4 v2 = *(const float4*)(wp2 + (k+2)*HC);
    float4 v3 = *(const float4*)(wp2 + (k+3)*HC);
    fma4(a0,xa.x,u0); fma4(a0,xa.y,u1); fma4(a0,xa.z,u2); fma4(a0,xa.w,u3);
    fma4(a1,xb.x,u0); fma4(a1,xb.y,u1); fma4(a1,xb.z,u2); fma4(a1,xb.w,u3);
    fma4(a2,xc.x,u0); fma4(a2,xc.y,u1); fma4(a2,xc.z,u2); fma4(a2,xc.w,u3);
    fma4(a3,xd.x,u0); fma4(a3,xd.y,u1); fma4(a3,xd.z,u2); fma4(a3,xd.w,u3);
    fma4(b0,xa.x,v0); fma4(b0,xa.y,v1); fma4(b0,xa.z,v2); fma4(b0,xa.w,v3);
    fma4(b1,xb.x,v0); fma4(b1,xb.y,v1); fma4(b1,xb.z,v2); fma4(b1,xb.w,v3);
    fma4(b2,xc.x,v0); fma4(b2,xc.y,v1); fma4(b2,xc.z,v2); fma4(b2,xc.w,v3);
    fma4(b3,xd.x,v0); fma4(b3,xd.y,v1); fma4(b3,xd.z,v2); fma4(b3,xd.w,v3);
  }
  float* o1 = out1 + (size_t)(bm+n0)*HC + cg*4;
  float* o2 = out2 + (size_t)(bm+n0)*HC + cg*4;
  *(float4*)(o1) = a0;
  *(float4*)(o2) = b0;
  if(n0+1<rows){ *(float4*)(o1+HC)   = a1; *(float4*)(o2+HC)   = b1; }
  if(n0+2<rows){ *(float4*)(o1+2*HC) = a2; *(float4*)(o2+2*HC) = b2; }
  if(n0+3<rows){ *(float4*)(o1+3*HC) = a3; *(float4*)(o2+3*HC) = b3; }
}

// ---------------- GAT gather: one block (128 thr) per dst node ----------------
__global__ void k_gat_gather(const int* __restrict__ rowptr, const int* __restrict__ csrc,
                             const float* __restrict__ hs,
                             const float* __restrict__ als, const float* __restrict__ ald,
                             const float* __restrict__ bias,
                             float* __restrict__ cat, int colOff, int nloop, int N){
  int n = blockIdx.x; if(n>=N) return;
  int f = threadIdx.x; if(f>=HC) return;
  int h = f/CD;
  float aldh = ald[n*2+h];
  float bi_f = bias[f];
  float acc = 0.f, z = 0.f;
  int e = rowptr[n], e1 = rowptr[n+1];
  for(; e<e1; e++){
    int s = csrc[e];
    float lg = als[s*2+h] + aldh;
    lg = lg>0.f ? lg : 0.2f*lg;
    float ev = __expf(lg);
    z += ev;
    acc += ev*hs[(size_t)s*HC+f];
  }
  if(n<nloop){
    float lg = als[n*2+h] + aldh;
    lg = lg>0.f ? lg : 0.2f*lg;
    float ev = __expf(lg);
    z += ev;
    acc += ev*hs[(size_t)n*HC+f];
  }
  cat[(size_t)n*DF + colOff + f] = acc/(z+1e-16f) + bi_f;
}

// ---------------- graph-LN stats only, one block per graph ----------------
__global__ void k_ln_stats2(const float* __restrict__ cat, const int* __restrict__ batch,
                            float* __restrict__ gs, float* __restrict__ gq, float* __restrict__ gc, int N){
  int g = blockIdx.x, start, end;
  seg_range(batch, N, g, start, end);
  const float4* c4 = (const float4*)cat;
  int i0 = start*(DF/4), i1 = end*(DF/4);
  float s=0.f, q=0.f;
  for(int i=i0+threadIdx.x; i<i1; i+=blockDim.x){
    float4 v = c4[i];
    s += v.x+v.y+v.z+v.w;
    q += v.x*v.x+v.y*v.y+v.z*v.z+v.w*v.w;
  }
  for(int o=32;o;o>>=1){ s+=__shfl_down(s,o); q+=__shfl_down(q,o); }
  __shared__ float ss[8], sq[8];
  int wv = threadIdx.x>>6;
  if((threadIdx.x&63)==0){ ss[wv]=s; sq[wv]=q; }
  __syncthreads();
  if(threadIdx.x==0){
    float S=0.f, Q=0.f;
    int nw = blockDim.x>>6;
    for(int k=0;k<nw;k++){ S+=ss[k]; Q+=sq[k]; }
    gs[g]=S; gq[g]=Q; gc[g]=(float)(end-start);
  }
}

// ---------------- fused: graph-LN normalize + elu (in place) + up to 2 attention GEMV pairs ----------------
__global__ void k_ln_norm_f(float* __restrict__ x, const int* __restrict__ batch,
                            const float* __restrict__ gs, const float* __restrict__ gq, const float* __restrict__ gc,
                            const float* __restrict__ wv, const float* __restrict__ bv,
                            const float* __restrict__ V0, float* __restrict__ o0,
                            const float* __restrict__ V1, float* __restrict__ o1, int N){
  int n = blockIdx.x*4 + (threadIdx.x>>6);
  if(n>=N) return;
  int lane = threadIdx.x & 63;
  int g = batch[n];
  float norm = fmaxf(gc[g],1.f)*(float)DF;
  float mean = gs[g]/norm;
  float var  = fmaxf(gq[g]/norm - mean*mean, 0.f);
  float rs   = rsqrtf(var+1e-5f);
  float2* xr = (float2*)(x + (size_t)n*DF);
  float a00=0,a01=0,a10=0,a11=0;
  for(int k2=lane;k2<DF/2;k2+=64){
    float2 x2 = xr[k2];
    float2 w2 = ((const float2*)wv)[k2];
    float2 b2 = ((const float2*)bv)[k2];
    float v0 = eluf((x2.x-mean)*rs*w2.x + b2.x);
    float v1 = eluf((x2.y-mean)*rs*w2.y + b2.y);
    xr[k2] = make_float2(v0,v1);
    float4 vv = ((const float4*)V0)[k2];
    a00 += v0*vv.x + v1*vv.z;  a01 += v0*vv.y + v1*vv.w;
    if(V1){
      float4 u = ((const float4*)V1)[k2];
      a10 += v0*u.x + v1*u.z;  a11 += v0*u.y + v1*u.w;
    }
  }
  for(int o=32;o;o>>=1){
    a00+=__shfl_down(a00,o); a01+=__shfl_down(a01,o);
    a10+=__shfl_down(a10,o); a11+=__shfl_down(a11,o);
  }
  if(lane==0){
    o0[n*2]=a00; o0[n*2+1]=a01;
    if(o1){ o1[n*2]=a10; o1[n*2+1]=a11; }
  }
}

// ---------------- SAG: sagg[n] = sum over in-edges of y2[src] ----------------
__global__ void k_sag_gather(const int* __restrict__ rowptr, const int* __restrict__ csrc,
                             const float* __restrict__ y2, float* __restrict__ sagg, int N){
  int n = blockIdx.x*blockDim.x + threadIdx.x;
  if(n>=N) return;
  float s=0.f;
  int e1 = rowptr[n+1];
  for(int e=rowptr[n]; e<e1; e++) s += y2[csrc[e]*2];
  sagg[n] = s;
}

// ---------------- SAG: en[n]=exp(score); zg[g]+=en ----------------
__global__ void k_sag_exp(const float* __restrict__ sagg, const float* __restrict__ y2,
                          const float* __restrict__ brel,
                          float* __restrict__ en, float* __restrict__ zg,
                          const int* __restrict__ batch, int N){
  int n = blockIdx.x*blockDim.x + threadIdx.x;
  if(n>=N) return;
  float sc = sagg[n] + brel[0] + y2[n*2+1];
  float e = __expf(sc);
  en[n] = e;
  atomicAdd(&zg[batch[n]], e);
}

// ---------------- SAG: out = x * alpha ----------------
__global__ void k_sag_out(const float* __restrict__ x, const float* __restrict__ en,
                          const float* __restrict__ zg, const int* __restrict__ batch,
                          float* __restrict__ out, int N){
  int i = blockIdx.x*blockDim.x + threadIdx.x;
  if(i>=N*DF) return;
  int n = i/DF;
  float a = en[n]/(zg[batch[n]]+1e-16f);
  out[i] = x[i]*a;
}

// ---------------- per-graph readout ----------------
__global__ void k_graph_sum(const float* __restrict__ x, const float* __restrict__ en,
                            const float* __restrict__ zg, const int* __restrict__ batch,
                            float* __restrict__ outg, int N){
  int g = blockIdx.x, start, end;
  seg_range(batch, N, g, start, end);
  int f = threadIdx.x;
  if(f>=DF) return;
  float s = 0.f;
  int n = start;
  for(; n+4<=end; n+=4){
    s += x[(size_t) n   *DF+f]*en[n]
       + x[(size_t)(n+1)*DF+f]*en[n+1]
       + x[(size_t)(n+2)*DF+f]*en[n+2]
       + x[(size_t)(n+3)*DF+f]*en[n+3];
  }
  for(; n<end; n++) s += x[(size_t)n*DF+f]*en[n];
  outg[(size_t)g*DF+f] = s/(zg[g]+1e-16f);
}

extern "C" void kernel_launch(void* const* d_in, const int* in_sizes, int n_in,
                              void* d_out, int out_size, void* d_ws, size_t ws_size,
                              hipStream_t stream){
  const float* atom_x    = (const float*)d_in[0];
  const int*   atom_ei   = (const int*)  d_in[1];
  const int*   atom_batch= (const int*)  d_in[2];
  const float* aa_x      = (const float*)d_in[3];
  const int*   aa_ei     = (const int*)  d_in[4];
  /* d_in[5] aa_edge_attr: ignored (GATConv has no edge_dim) */
  const int*   aa_batch  = (const int*)  d_in[6];
  const int*   m2p       = (const int*)  d_in[7];
  const float* Wd     =(const float*)d_in[8];
  const float* ad_src =(const float*)d_in[9];
  const float* ad_dst =(const float*)d_in[10];
  const float* bd     =(const float*)d_in[11];
  const float* Wp     =(const float*)d_in[12];
  const float* ap_src =(const float*)d_in[13];
  const float* ap_dst =(const float*)d_in[14];
  const float* bp     =(const float*)d_in[15];
  const float* Wi_src =(const float*)d_in[16];
  const float* Wi_dst =(const float*)d_in[17];
  const float* ai_src =(const float*)d_in[18];
  const float* ai_dst =(const float*)d_in[19];
  const float* bi     =(const float*)d_in[20];
  const float* ln_d_w =(const float*)d_in[21];
  const float* ln_d_b =(const float*)d_in[22];
  const float* ln_p_w =(const float*)d_in[23];
  const float* ln_p_b =(const float*)d_in[24];
  const float* pd_Wrel=(const float*)d_in[25];
  const float* pd_brel=(const float*)d_in[26];
  const float* pd_Wroot=(const float*)d_in[27];
  const float* pp_Wrel=(const float*)d_in[28];
  const float* pp_brel=(const float*)d_in[29];
  const float* pp_Wroot=(const float*)d_in[30];

  const int nA = in_sizes[0]/DF;     // 25600 atoms
  const int EA = in_sizes[1]/2;      // 102400 atom edges
  const int nP = in_sizes[3]/DF;     // 204800 aa nodes
  const int EP = in_sizes[4]/2;      // 1024000 aa edges
  const int EM = in_sizes[7]/2;      // 512000 m2p edges
  const int nLoop = nA<nP ? nA : nP;

  float* w = (float*)d_ws;
  size_t off = 0;
  auto alloc = [&](size_t n){ float* p = w+off; off += (n+63)&~(size_t)63; return p; };

  float* AX  = alloc((size_t)nA*DF);   // atom_cat -> atom_h
  float* AB  = alloc((size_t)nP*DF);   // aa_cat   -> aa_h
  float* H1  = alloc((size_t)nA*HC);   // h1 (atom@Wd), later hs4 (atom_h@Wi_src)
  float* HS2 = alloc((size_t)nP*HC);   // aa@Wi_src
  float* H3  = alloc((size_t)nP*HC);   // aa@Wp
  float* als1=alloc((size_t)nA*2); float* ald1=alloc((size_t)nA*2);
  float* als2=alloc((size_t)nP*2); float* ald2=alloc((size_t)nA*2);
  float* als3=alloc((size_t)nP*2); float* ald3=alloc((size_t)nP*2);
  float* als4=alloc((size_t)nA*2); float* ald4=alloc((size_t)nP*2);
  float* Vds=alloc(DF*2); float* Vdd=alloc(DF*2);
  float* Vps=alloc(DF*2); float* Vpd=alloc(DF*2);
  float* Vis=alloc(DF*2); float* Vid=alloc(DF*2);
  float* VsA=alloc(DF*2); float* VsP=alloc(DF*2);
  float* y2A=alloc((size_t)nA*2); float* y2P=alloc((size_t)nP*2);
  float* enA=alloc(nA);   float* enP=alloc(nP);
  float* gsA=alloc(NG); float* gqA=alloc(NG); float* gcA=alloc(NG);
  float* gsP=alloc(NG); float* gqP=alloc(NG); float* gcP=alloc(NG);
  float* saggA=alloc(nA); float* saggP=alloc(nP);
  // CSR arrays (int, stored in float slots)
  int* srcAi = (int*)alloc(EA);         // atom-intra src list
  int* srcAm = (int*)alloc(EM);         // m2p->atom src list (aa ids)
  int* srcPi = (int*)alloc(EP);         // aa-intra src list
  int* srcPm = (int*)alloc(EM);         // m2p->aa src list (atom ids)
  int* curAi = (int*)alloc(nA); int* curAm = (int*)alloc(nA);
  int* curPi = (int*)alloc(nP); int* curPm = (int*)alloc(nP);
  int* bsum  = (int*)alloc(1024);
  // ---- contiguous zero region: rowptrs (hist accumulators) + zg ----
  float* zr0 = w+off;
  int* rpAi = (int*)alloc(nA+1); int* rpAm = (int*)alloc(nA+1);
  int* rpPi = (int*)alloc(nP+1); int* rpPm = (int*)alloc(nP+1);
  float* zgA=alloc(NG); float* zgP=alloc(NG);
  size_t zrBytes = ((w+off) - zr0)*sizeof(float);
  if(off*sizeof(float) > ws_size) return; // workspace too small — bail

  float* out_atom = (float*)d_out;
  float* out_aa   = out_atom + (size_t)nA*DF;
  float* out_dg   = out_aa   + (size_t)nP*DF;
  float* out_pg   = out_dg   + (size_t)NG*DF;

  const int B = 256;
  hipMemsetAsync(zr0, 0, zrBytes, stream);

  // ---- CSR builds (4 edge sets, dst-indexed; store src directly) ----
  auto buildCSR = [&](const int* esrc, const int* edst, int E, int N,
                      int* rowptr, int* cursor, int* csrc){
    int nb = (N+SCB-1)/SCB;
    k_hist <<<(E+B-1)/B, B, 0, stream>>>(edst, E, rowptr);
    k_scan1<<<nb, SCB, 0, stream>>>(rowptr, N, bsum);
    k_scan2<<<1, 1024, 0, stream>>>(bsum, nb);
    k_scan3<<<nb, SCB, 0, stream>>>(rowptr, cursor, bsum, N, E);
    k_fill <<<(E+B-1)/B, B, 0, stream>>>(esrc, edst, E, cursor, csrc);
  };
  buildCSR(atom_ei,      atom_ei+EA, EA, nA, rpAi, curAi, srcAi);  // atom intra
  buildCSR(m2p+EM,       m2p,        EM, nA, rpAm, curAm, srcAm);  // m2p -> atom (src=aa)
  buildCSR(aa_ei,        aa_ei+EP,   EP, nP, rpPi, curPi, srcPi);  // aa intra
  buildCSR(m2p,          m2p+EM,     EM, nP, rpPm, curPm, srcPm);  // m2p -> aa (src=atom)

  // 1. fused attention vectors
  k_makeV<<<2,B,0,stream>>>(Wd,     ad_src, Vds);
  k_makeV<<<2,B,0,stream>>>(Wd,     ad_dst, Vdd);
  k_makeV<<<2,B,0,stream>>>(Wp,     ap_src, Vps);
  k_makeV<<<2,B,0,stream>>>(Wp,     ap_dst, Vpd);
  k_makeV<<<2,B,0,stream>>>(Wi_src, ai_src, Vis);
  k_makeV<<<2,B,0,stream>>>(Wi_dst, ai_dst, Vid);
  k_pack2<<<1,B,0,stream>>>(pd_Wrel, pd_Wroot, VsA);
  k_pack2<<<1,B,0,stream>>>(pp_Wrel, pp_Wroot, VsP);

  // 2. GEMMs (LDS-tiled, elu fused into X load) + attention GEMVs (elu inline)
  k_gemm_t<1><<<(nA+TM-1)/TM, B, 0, stream>>>(atom_x, Wd, H1, nA);
  k_gemm2_t<1><<<(nP+TM-1)/TM, B, 0, stream>>>(aa_x, Wi_src, Wp, HS2, H3, nP);
  k_gemv3<<<(nA+3)/4,B,0,stream>>>(atom_x, Vds, Vdd, Vid, als1, ald1, ald2, nA);
  k_gemv4<<<(nP+3)/4,B,0,stream>>>(aa_x, Vis, Vps, Vpd, Vid, als2, als3, ald3, ald4, nP);

  // 3. GAT gathers (write AX/AB; softmax denom + bias fused; no atomics, no memset)
  k_gat_gather<<<nA,128,0,stream>>>(rpAi, srcAi, H1,  als1, ald1, bd, AX, 0,  nA,    nA);
  k_gat_gather<<<nA,128,0,stream>>>(rpAm, srcAm, HS2, als2, ald2, bi, AX, HC, nLoop, nA);
  k_gat_gather<<<nP,128,0,stream>>>(rpPi, srcPi, H3,  als3, ald3, bp, AB, 0,  nP,    nP);

  // 4. atom: LN stats + fused norm/elu/GEMVs
  k_ln_stats2<<<NG,512,0,stream>>>(AX, atom_batch, gsA, gqA, gcA, nA);
  k_ln_norm_f<<<(nA+3)/4,B,0,stream>>>(AX, atom_batch, gsA, gqA, gcA, ln_d_w, ln_d_b,
                                       Vis, als4, VsA, y2A, nA);

  // 5. hs4 = atom_h @ Wi_src (reuse H1, no elu — AX already activated); GAT4 gather
  k_gemm_t<0><<<(nA+TM-1)/TM, B, 0, stream>>>(AX, Wi_src, H1, nA);
  k_gat_gather<<<nP,128,0,stream>>>(rpPm, srcPm, H1, als4, ald4, bi, AB, HC, nLoop, nP);

  // 6. aa: LN stats + fused norm/elu/y2 GEMV
  k_ln_stats2<<<NG,512,0,stream>>>(AB, aa_batch, gsP, gqP, gcP, nP);
  k_ln_norm_f<<<(nP+3)/4,B,0,stream>>>(AB, aa_batch, gsP, gqP, gcP, ln_p_w, ln_p_b,
                                       VsP, y2P, (const float*)nullptr, (float*)nullptr, nP);

  // 7. SAG pool atom + readout
  k_sag_gather<<<(nA+B-1)/B,B,0,stream>>>(rpAi, srcAi, y2A, saggA, nA);
  k_sag_exp<<<(nA+B-1)/B,B,0,stream>>>(saggA, y2A, pd_brel, enA, zgA, atom_batch, nA);
  k_sag_out<<<(nA*DF+B-1)/B,B,0,stream>>>(AX, enA, zgA, atom_batch, out_atom, nA);
  k_graph_sum<<<NG,B,0,stream>>>(AX, enA, zgA, atom_batch, out_dg, nA);

  // 8. SAG pool aa + readout
  k_sag_gather<<<(nP+B-1)/B,B,0,stream>>>(rpPi, srcPi, y2P, saggP, nP);
  k_sag_exp<<<(nP+B-1)/B,B,0,stream>>>(saggP, y2P, pp_brel, enP, zgP, aa_batch, nP);
  k_sag_out<<<(nP*DF+B-1)/B,B,0,stream>>>(AB, enP, zgP, aa_batch, out_aa, nP);
  k_graph_sum<<<NG,B,0,stream>>>(AB, enP, zgP, aa_batch, out_pg, nP);
}